// Round 1
// baseline (5733.325 us; speedup 1.0000x reference)
//
#include <hip/hip_runtime.h>

#define NN 100000
#define DD 128
#define CC 40

// ---------------------------------------------------------------------------
// hardware f32 atomic add (global_atomic_add_f32, avoids CAS loop)
__device__ __forceinline__ void fadd(float* p, float v) { unsafeAtomicAdd(p, v); }

// ---------------------------------------------------------------------------
// degree count: cnt[dst[e]] += 1
__global__ __launch_bounds__(256)
void k_count(const int* __restrict__ dst, float* __restrict__ cnt, int E) {
    int i = blockIdx.x * 256 + threadIdx.x;
    if (i < E) fadd(&cnt[dst[i]], 1.0f);
}

// ---------------------------------------------------------------------------
// feature scatter: agg[dst[e]][:] += in[src[e]][:]
// 32 lanes (half wave) per edge, float4 per lane -> 512B coalesced gather
__global__ __launch_bounds__(256)
void k_scatter(const int* __restrict__ src, const int* __restrict__ dst,
               const float* __restrict__ xin, float* __restrict__ agg, int E) {
    int t = blockIdx.x * 256 + threadIdx.x;
    int e = t >> 5;
    if (e >= E) return;
    int fq = (t & 31) << 2;
    int s = src[e], d = dst[e];
    float4 v = *reinterpret_cast<const float4*>(xin + (size_t)s * DD + fq);
    float* b = agg + (size_t)d * DD + fq;
    fadd(b + 0, v.x); fadd(b + 1, v.y); fadd(b + 2, v.z); fadd(b + 3, v.w);
}

// ---------------------------------------------------------------------------
// fused SAGE linear: out = relu((agg/max(cnt,1)) @ Wl^T + bl + xin @ Wr^T)
// block: 32 rows x 128 cols, 256 threads, 4x4 register tile, K chunked by 32
__global__ __launch_bounds__(256)
void k_linear(const float* __restrict__ agg, const float* __restrict__ cnt,
              const float* __restrict__ xin,
              const float* __restrict__ Wl, const float* __restrict__ bl,
              const float* __restrict__ Wr, float* __restrict__ out)
{
    __shared__ float sWT[32][132];   // [k][c], pitch 132 floats (528B, 16B-aligned)
    __shared__ float sInT[32][36];   // [k][r], pitch 36 floats (144B, 16B-aligned)
    const int tid = threadIdx.x;
    const int row0 = blockIdx.x * 32;
    const int tc = tid & 31, tr = tid >> 5;
    const int c0 = tc * 4, r0 = tr * 4;

    float acc[4][4] = {};

    for (int phase = 0; phase < 2; ++phase) {
        const float* W  = phase ? Wr : Wl;
        const float* In = phase ? xin : agg;
        for (int kb = 0; kb < 128; kb += 32) {
            // stage W chunk transposed: sWT[k][c] = W[c][kb+k]
            #pragma unroll
            for (int i = 0; i < 4; ++i) {
                int idx = tid + i * 256;          // 0..1023
                int c = idx >> 3, kq = (idx & 7) << 2;
                float4 w = *reinterpret_cast<const float4*>(W + c * DD + kb + kq);
                sWT[kq + 0][c] = w.x; sWT[kq + 1][c] = w.y;
                sWT[kq + 2][c] = w.z; sWT[kq + 3][c] = w.w;
            }
            // stage input chunk transposed (mean-scaled in phase 0)
            {
                int r = tid >> 3, kq = (tid & 7) << 2;
                float4 v = *reinterpret_cast<const float4*>(
                    In + (size_t)(row0 + r) * DD + kb + kq);
                if (phase == 0) {
                    float s = 1.0f / fmaxf(cnt[row0 + r], 1.0f);
                    v.x *= s; v.y *= s; v.z *= s; v.w *= s;
                }
                sInT[kq + 0][r] = v.x; sInT[kq + 1][r] = v.y;
                sInT[kq + 2][r] = v.z; sInT[kq + 3][r] = v.w;
            }
            __syncthreads();
            #pragma unroll
            for (int kk = 0; kk < 32; ++kk) {
                float4 w  = *reinterpret_cast<const float4*>(&sWT[kk][c0]);
                float4 xi = *reinterpret_cast<const float4*>(&sInT[kk][r0]);
                const float xv[4] = {xi.x, xi.y, xi.z, xi.w};
                const float wv[4] = {w.x, w.y, w.z, w.w};
                #pragma unroll
                for (int i = 0; i < 4; ++i)
                    #pragma unroll
                    for (int j = 0; j < 4; ++j)
                        acc[i][j] += xv[i] * wv[j];
            }
            __syncthreads();
        }
    }

    float4 b = *reinterpret_cast<const float4*>(bl + c0);
    const float bv[4] = {b.x, b.y, b.z, b.w};
    #pragma unroll
    for (int i = 0; i < 4; ++i) {
        float4 o;
        o.x = fmaxf(acc[i][0] + bv[0], 0.0f);
        o.y = fmaxf(acc[i][1] + bv[1], 0.0f);
        o.z = fmaxf(acc[i][2] + bv[2], 0.0f);
        o.w = fmaxf(acc[i][3] + bv[3], 0.0f);
        *reinterpret_cast<float4*>(out + (size_t)(row0 + r0 + i) * DD + c0) = o;
    }
}

// ---------------------------------------------------------------------------
// output layer: out = h @ Wout^T + bout   (N x 40), no relu
// 320 threads: 32 rows x 10 col-quads
__global__ __launch_bounds__(320)
void k_out(const float* __restrict__ h, const float* __restrict__ Wout,
           const float* __restrict__ bout, float* __restrict__ out)
{
    __shared__ float sW[128][44];    // [k][c], pitch 44 (176B, 16B-aligned)
    __shared__ float sH[32][132];
    const int tid = threadIdx.x;
    const int row0 = blockIdx.x * 32;

    #pragma unroll
    for (int i = 0; i < 16; ++i) {           // 40*128 = 5120 = 320*16
        int idx = tid + i * 320;
        int c = idx >> 7, k = idx & 127;
        sW[k][c] = Wout[idx];
    }
    for (int idx = tid; idx < 32 * 128; idx += 320) {
        int r = idx >> 7, k = idx & 127;
        sH[r][k] = h[(size_t)(row0 + r) * DD + k];
    }
    __syncthreads();

    const int r = tid / 10, c0 = (tid % 10) * 4;
    float4 b = *reinterpret_cast<const float4*>(bout + c0);
    float4 acc = b;
    #pragma unroll 4
    for (int k = 0; k < 128; ++k) {
        float hv = sH[r][k];
        float4 w = *reinterpret_cast<const float4*>(&sW[k][c0]);
        acc.x += hv * w.x; acc.y += hv * w.y;
        acc.z += hv * w.z; acc.w += hv * w.w;
    }
    *reinterpret_cast<float4*>(out + (size_t)(row0 + r) * CC + c0) = acc;
}

// ---------------------------------------------------------------------------
extern "C" void kernel_launch(void* const* d_in, const int* in_sizes, int n_in,
                              void* d_out, int out_size, void* d_ws, size_t ws_size,
                              hipStream_t stream)
{
    const float* x    = (const float*)d_in[0];
    const int*   ei   = (const int*)d_in[1];
    const float* Wl1  = (const float*)d_in[2];
    const float* bl1  = (const float*)d_in[3];
    const float* Wr1  = (const float*)d_in[4];
    const float* Wl2  = (const float*)d_in[5];
    const float* bl2  = (const float*)d_in[6];
    const float* Wr2  = (const float*)d_in[7];
    const float* Wout = (const float*)d_in[8];
    const float* bout = (const float*)d_in[9];
    float* out = (float*)d_out;

    const int E = in_sizes[1] / 2;
    const int* srcI = ei;        // edge_index[0]
    const int* dstI = ei + E;    // edge_index[1]

    // workspace layout: bufA [N*128] | cnt [N] | bufB [N*128]  (~103 MB)
    float* bufA = (float*)d_ws;
    float* cnt  = bufA + (size_t)NN * DD;
    float* bufB = cnt + NN;

    dim3 b256(256);
    const int sBlocks = (int)(((size_t)E * 32 + 255) / 256);

    // layer 1
    hipMemsetAsync(bufA, 0, ((size_t)NN * DD + NN) * sizeof(float), stream);
    k_count<<<(E + 255) / 256, b256, 0, stream>>>(dstI, cnt, E);
    k_scatter<<<sBlocks, b256, 0, stream>>>(srcI, dstI, x, bufA, E);
    k_linear<<<NN / 32, b256, 0, stream>>>(bufA, cnt, x, Wl1, bl1, Wr1, bufB);

    // layer 2 (in-place h2 into bufA; row-disjoint blocks, reads precede writes)
    hipMemsetAsync(bufA, 0, (size_t)NN * DD * sizeof(float), stream);
    k_scatter<<<sBlocks, b256, 0, stream>>>(srcI, dstI, bufB, bufA, E);
    k_linear<<<NN / 32, b256, 0, stream>>>(bufA, cnt, bufB, Wl2, bl2, Wr2, bufA);

    // classifier head
    k_out<<<NN / 32, dim3(320), 0, stream>>>(bufA, Wout, bout, out);
}

// Round 2
// 708.421 us; speedup vs baseline: 8.0931x; 8.0931x over previous
//
#include <hip/hip_runtime.h>

#define NN 100000
#define DD 128
#define CC 40
#define CHUNK 1024
#define NB ((NN + CHUNK - 1) / CHUNK)   // 98

// ---------------------------------------------------------------------------
// degree count: cnt[dst[e]] += 1  (int atomics, cheap)
__global__ __launch_bounds__(256)
void k_count(const int* __restrict__ dst, int* __restrict__ cnt, int E) {
    int i = blockIdx.x * 256 + threadIdx.x;
    if (i < E) atomicAdd(&cnt[dst[i]], 1);
}

// ---------------------------------------------------------------------------
// scan step 1: per-1024-chunk sums
__global__ __launch_bounds__(256)
void k_sumchunk(const int* __restrict__ cnt, int* __restrict__ bsum) {
    __shared__ int s[256];
    int t = threadIdx.x, b = blockIdx.x;
    int base = b * CHUNK + t * 4;
    int v = 0;
    #pragma unroll
    for (int k = 0; k < 4; ++k) { int i = base + k; if (i < NN) v += cnt[i]; }
    s[t] = v; __syncthreads();
    for (int off = 128; off > 0; off >>= 1) {
        if (t < off) s[t] += s[t + off];
        __syncthreads();
    }
    if (t == 0) bsum[b] = s[0];
}

// scan step 2: exclusive scan of the 98 chunk sums (single block)
__global__ __launch_bounds__(128)
void k_scanb(const int* __restrict__ bsum, int* __restrict__ boff,
             int* __restrict__ rowstart, int E) {
    __shared__ int s[128];
    int t = threadIdx.x;
    int v = (t < NB) ? bsum[t] : 0;
    s[t] = v; __syncthreads();
    for (int off = 1; off < 128; off <<= 1) {
        int add = (t >= off) ? s[t - off] : 0;
        __syncthreads();
        s[t] += add;
        __syncthreads();
    }
    if (t < NB) boff[t] = s[t] - v;      // exclusive
    if (t == 0) rowstart[NN] = E;
}

// scan step 3: full exclusive scan -> rowstart + cursor
__global__ __launch_bounds__(256)
void k_scanfinal(const int* __restrict__ cnt, const int* __restrict__ boff,
                 int* __restrict__ rowstart, int* __restrict__ cursor) {
    __shared__ int s[256];
    int t = threadIdx.x, b = blockIdx.x;
    int base = b * CHUNK + t * 4;
    int v[4];
    #pragma unroll
    for (int k = 0; k < 4; ++k) { int i = base + k; v[k] = (i < NN) ? cnt[i] : 0; }
    int tsum = v[0] + v[1] + v[2] + v[3];
    s[t] = tsum; __syncthreads();
    for (int off = 1; off < 256; off <<= 1) {
        int add = (t >= off) ? s[t - off] : 0;
        __syncthreads();
        s[t] += add;
        __syncthreads();
    }
    int ex = s[t] - tsum + boff[b];
    int run = ex;
    #pragma unroll
    for (int k = 0; k < 4; ++k) {
        int i = base + k;
        if (i < NN) { rowstart[i] = run; cursor[i] = run; }
        run += v[k];
    }
}

// CSR fill: adj[cursor[dst[e]]++] = src[e]
__global__ __launch_bounds__(256)
void k_fill(const int* __restrict__ src, const int* __restrict__ dst,
            int* __restrict__ cursor, int* __restrict__ adj, int E) {
    int e = blockIdx.x * 256 + threadIdx.x;
    if (e >= E) return;
    int pos = atomicAdd(&cursor[dst[e]], 1);
    adj[pos] = src[e];
}

// ---------------------------------------------------------------------------
// gather-aggregate: one wave per node, float2 per lane; writes the MEAN
__global__ __launch_bounds__(256)
void k_aggregate(const int* __restrict__ rowstart, const int* __restrict__ adj,
                 const float* __restrict__ xin, float* __restrict__ outm) {
    int w = (blockIdx.x * 256 + threadIdx.x) >> 6;   // node id
    if (w >= NN) return;
    int lane = threadIdx.x & 63;
    int beg = rowstart[w], end = rowstart[w + 1];
    float2 a0 = {0.f, 0.f}, a1 = {0.f, 0.f};
    int j = beg;
    for (; j + 1 < end; j += 2) {
        int s0 = adj[j], s1 = adj[j + 1];
        float2 v0 = *reinterpret_cast<const float2*>(xin + (size_t)s0 * DD + lane * 2);
        float2 v1 = *reinterpret_cast<const float2*>(xin + (size_t)s1 * DD + lane * 2);
        a0.x += v0.x; a0.y += v0.y;
        a1.x += v1.x; a1.y += v1.y;
    }
    if (j < end) {
        int s0 = adj[j];
        float2 v0 = *reinterpret_cast<const float2*>(xin + (size_t)s0 * DD + lane * 2);
        a0.x += v0.x; a0.y += v0.y;
    }
    float inv = 1.0f / fmaxf((float)(end - beg), 1.0f);
    float2 o; o.x = (a0.x + a1.x) * inv; o.y = (a0.y + a1.y) * inv;
    *reinterpret_cast<float2*>(outm + (size_t)w * DD + lane * 2) = o;
}

// ---------------------------------------------------------------------------
// fused SAGE linear: out = relu(mean @ Wl^T + bl + xin @ Wr^T)
__global__ __launch_bounds__(256)
void k_linear(const float* __restrict__ mean, const float* __restrict__ xin,
              const float* __restrict__ Wl, const float* __restrict__ bl,
              const float* __restrict__ Wr, float* __restrict__ out)
{
    __shared__ float sWT[32][132];
    __shared__ float sInT[32][36];
    const int tid = threadIdx.x;
    const int row0 = blockIdx.x * 32;
    const int tc = tid & 31, tr = tid >> 5;
    const int c0 = tc * 4, r0 = tr * 4;

    float acc[4][4] = {};

    for (int phase = 0; phase < 2; ++phase) {
        const float* W  = phase ? Wr : Wl;
        const float* In = phase ? xin : mean;
        for (int kb = 0; kb < 128; kb += 32) {
            #pragma unroll
            for (int i = 0; i < 4; ++i) {
                int idx = tid + i * 256;
                int c = idx >> 3, kq = (idx & 7) << 2;
                float4 w = *reinterpret_cast<const float4*>(W + c * DD + kb + kq);
                sWT[kq + 0][c] = w.x; sWT[kq + 1][c] = w.y;
                sWT[kq + 2][c] = w.z; sWT[kq + 3][c] = w.w;
            }
            {
                int r = tid >> 3, kq = (tid & 7) << 2;
                float4 v = *reinterpret_cast<const float4*>(
                    In + (size_t)(row0 + r) * DD + kb + kq);
                sInT[kq + 0][r] = v.x; sInT[kq + 1][r] = v.y;
                sInT[kq + 2][r] = v.z; sInT[kq + 3][r] = v.w;
            }
            __syncthreads();
            #pragma unroll
            for (int kk = 0; kk < 32; ++kk) {
                float4 w  = *reinterpret_cast<const float4*>(&sWT[kk][c0]);
                float4 xi = *reinterpret_cast<const float4*>(&sInT[kk][r0]);
                const float xv[4] = {xi.x, xi.y, xi.z, xi.w};
                const float wv[4] = {w.x, w.y, w.z, w.w};
                #pragma unroll
                for (int i = 0; i < 4; ++i)
                    #pragma unroll
                    for (int j = 0; j < 4; ++j)
                        acc[i][j] += xv[i] * wv[j];
            }
            __syncthreads();
        }
    }

    float4 b = *reinterpret_cast<const float4*>(bl + c0);
    const float bv[4] = {b.x, b.y, b.z, b.w};
    #pragma unroll
    for (int i = 0; i < 4; ++i) {
        float4 o;
        o.x = fmaxf(acc[i][0] + bv[0], 0.0f);
        o.y = fmaxf(acc[i][1] + bv[1], 0.0f);
        o.z = fmaxf(acc[i][2] + bv[2], 0.0f);
        o.w = fmaxf(acc[i][3] + bv[3], 0.0f);
        *reinterpret_cast<float4*>(out + (size_t)(row0 + r0 + i) * DD + c0) = o;
    }
}

// ---------------------------------------------------------------------------
// output layer: out = h @ Wout^T + bout   (N x 40)
__global__ __launch_bounds__(320)
void k_out(const float* __restrict__ h, const float* __restrict__ Wout,
           const float* __restrict__ bout, float* __restrict__ out)
{
    __shared__ float sW[128][44];
    __shared__ float sH[32][132];
    const int tid = threadIdx.x;
    const int row0 = blockIdx.x * 32;

    #pragma unroll
    for (int i = 0; i < 16; ++i) {
        int idx = tid + i * 320;
        int c = idx >> 7, k = idx & 127;
        sW[k][c] = Wout[idx];
    }
    for (int idx = tid; idx < 32 * 128; idx += 320) {
        int r = idx >> 7, k = idx & 127;
        sH[r][k] = h[(size_t)(row0 + r) * DD + k];
    }
    __syncthreads();

    const int r = tid / 10, c0 = (tid % 10) * 4;
    float4 b = *reinterpret_cast<const float4*>(bout + c0);
    float4 acc = b;
    #pragma unroll 4
    for (int k = 0; k < 128; ++k) {
        float hv = sH[r][k];
        float4 w = *reinterpret_cast<const float4*>(&sW[k][c0]);
        acc.x += hv * w.x; acc.y += hv * w.y;
        acc.z += hv * w.z; acc.w += hv * w.w;
    }
    *reinterpret_cast<float4*>(out + (size_t)(row0 + r) * CC + c0) = acc;
}

// ---------------------------------------------------------------------------
extern "C" void kernel_launch(void* const* d_in, const int* in_sizes, int n_in,
                              void* d_out, int out_size, void* d_ws, size_t ws_size,
                              hipStream_t stream)
{
    const float* x    = (const float*)d_in[0];
    const int*   ei   = (const int*)d_in[1];
    const float* Wl1  = (const float*)d_in[2];
    const float* bl1  = (const float*)d_in[3];
    const float* Wr1  = (const float*)d_in[4];
    const float* Wl2  = (const float*)d_in[5];
    const float* bl2  = (const float*)d_in[6];
    const float* Wr2  = (const float*)d_in[7];
    const float* Wout = (const float*)d_in[8];
    const float* bout = (const float*)d_in[9];
    float* out = (float*)d_out;

    const int E = in_sizes[1] / 2;
    const int* srcI = ei;        // edge_index[0]
    const int* dstI = ei + E;    // edge_index[1]

    // workspace layout (floats first for 16B alignment):
    // bufA [N*128] | bufB [N*128] | cnt [N] | rowstart [N+1] | cursor [N] |
    // bsum [NB] | boff [NB] | adj [E]
    float* bufA = (float*)d_ws;
    float* bufB = bufA + (size_t)NN * DD;
    int* cnt      = (int*)(bufB + (size_t)NN * DD);
    int* rowstart = cnt + NN;
    int* cursor   = rowstart + NN + 1;
    int* bsum     = cursor + NN;
    int* boff     = bsum + NB;
    int* adj      = boff + NB;

    dim3 b256(256);
    const int aggBlocks = (NN * 64 + 255) / 256;   // one wave per node

    // ---- CSR build (shared by both layers)
    hipMemsetAsync(cnt, 0, NN * sizeof(int), stream);
    k_count<<<(E + 255) / 256, b256, 0, stream>>>(dstI, cnt, E);
    k_sumchunk<<<NB, b256, 0, stream>>>(cnt, bsum);
    k_scanb<<<1, dim3(128), 0, stream>>>(bsum, boff, rowstart, E);
    k_scanfinal<<<NB, b256, 0, stream>>>(cnt, boff, rowstart, cursor);
    k_fill<<<(E + 255) / 256, b256, 0, stream>>>(srcI, dstI, cursor, adj, E);

    // ---- layer 1
    k_aggregate<<<aggBlocks, b256, 0, stream>>>(rowstart, adj, x, bufA);
    k_linear<<<NN / 32, b256, 0, stream>>>(bufA, x, Wl1, bl1, Wr1, bufB);

    // ---- layer 2 (in-place h2 into bufA)
    k_aggregate<<<aggBlocks, b256, 0, stream>>>(rowstart, adj, bufB, bufA);
    k_linear<<<NN / 32, b256, 0, stream>>>(bufA, bufB, Wl2, bl2, Wr2, bufA);

    // ---- classifier head
    k_out<<<NN / 32, dim3(320), 0, stream>>>(bufA, Wout, bout, out);
}

// Round 3
// 622.452 us; speedup vs baseline: 9.2109x; 1.1381x over previous
//
#include <hip/hip_runtime.h>

#define NN 100000
#define DD 128
#define CC 40
#define CHUNK 1024
#define NB ((NN + CHUNK - 1) / CHUNK)   // 98

typedef unsigned int  uint;
typedef unsigned short ushort;

// bf16 helpers (bit-level, round-to-nearest-even)
__device__ __forceinline__ float blo(uint u) { return __uint_as_float(u << 16); }
__device__ __forceinline__ float bhi(uint u) { return __uint_as_float(u & 0xFFFF0000u); }
__device__ __forceinline__ uint  f2b(float f) {
    uint u = __float_as_uint(f);
    return (u + 0x7FFFu + ((u >> 16) & 1u)) >> 16;
}
__device__ __forceinline__ uint pack2(float lo, float hi) { return f2b(lo) | (f2b(hi) << 16); }

// ---------------------------------------------------------------------------
// x (f32) -> xh (bf16), 8 elems/thread
__global__ __launch_bounds__(256)
void k_cvt(const float* __restrict__ x, uint* __restrict__ xh, int n8) {
    int i = blockIdx.x * 256 + threadIdx.x;
    if (i >= n8) return;
    float4 a = reinterpret_cast<const float4*>(x)[i * 2];
    float4 b = reinterpret_cast<const float4*>(x)[i * 2 + 1];
    uint4 o;
    o.x = pack2(a.x, a.y); o.y = pack2(a.z, a.w);
    o.z = pack2(b.x, b.y); o.w = pack2(b.z, b.w);
    reinterpret_cast<uint4*>(xh)[i] = o;
}

// ---------------------------------------------------------------------------
// degree count
__global__ __launch_bounds__(256)
void k_count(const int* __restrict__ dst, int* __restrict__ cnt, int E) {
    int i = blockIdx.x * 256 + threadIdx.x;
    if (i < E) atomicAdd(&cnt[dst[i]], 1);
}

__global__ __launch_bounds__(256)
void k_sumchunk(const int* __restrict__ cnt, int* __restrict__ bsum) {
    __shared__ int s[256];
    int t = threadIdx.x, b = blockIdx.x;
    int base = b * CHUNK + t * 4;
    int v = 0;
    #pragma unroll
    for (int k = 0; k < 4; ++k) { int i = base + k; if (i < NN) v += cnt[i]; }
    s[t] = v; __syncthreads();
    for (int off = 128; off > 0; off >>= 1) {
        if (t < off) s[t] += s[t + off];
        __syncthreads();
    }
    if (t == 0) bsum[b] = s[0];
}

__global__ __launch_bounds__(128)
void k_scanb(const int* __restrict__ bsum, int* __restrict__ boff,
             int* __restrict__ rowstart, int E) {
    __shared__ int s[128];
    int t = threadIdx.x;
    int v = (t < NB) ? bsum[t] : 0;
    s[t] = v; __syncthreads();
    for (int off = 1; off < 128; off <<= 1) {
        int add = (t >= off) ? s[t - off] : 0;
        __syncthreads();
        s[t] += add;
        __syncthreads();
    }
    if (t < NB) boff[t] = s[t] - v;
    if (t == 0) rowstart[NN] = E;
}

__global__ __launch_bounds__(256)
void k_scanfinal(const int* __restrict__ cnt, const int* __restrict__ boff,
                 int* __restrict__ rowstart, int* __restrict__ cursor) {
    __shared__ int s[256];
    int t = threadIdx.x, b = blockIdx.x;
    int base = b * CHUNK + t * 4;
    int v[4];
    #pragma unroll
    for (int k = 0; k < 4; ++k) { int i = base + k; v[k] = (i < NN) ? cnt[i] : 0; }
    int tsum = v[0] + v[1] + v[2] + v[3];
    s[t] = tsum; __syncthreads();
    for (int off = 1; off < 256; off <<= 1) {
        int add = (t >= off) ? s[t - off] : 0;
        __syncthreads();
        s[t] += add;
        __syncthreads();
    }
    int ex = s[t] - tsum + boff[b];
    int run = ex;
    #pragma unroll
    for (int k = 0; k < 4; ++k) {
        int i = base + k;
        if (i < NN) { rowstart[i] = run; cursor[i] = run; }
        run += v[k];
    }
}

__global__ __launch_bounds__(256)
void k_fill(const int* __restrict__ src, const int* __restrict__ dst,
            int* __restrict__ cursor, int* __restrict__ adj, int E) {
    int e = blockIdx.x * 256 + threadIdx.x;
    if (e >= E) return;
    int pos = atomicAdd(&cursor[dst[e]], 1);
    adj[pos] = src[e];
}

// ---------------------------------------------------------------------------
// gather-aggregate over bf16 rows: one wave/node, 1 uint (2 bf16) per lane
__global__ __launch_bounds__(256)
void k_aggregate(const int* __restrict__ rowstart, const int* __restrict__ adj,
                 const uint* __restrict__ xh, uint* __restrict__ outm) {
    int w = (blockIdx.x * 256 + threadIdx.x) >> 6;   // node id
    if (w >= NN) return;
    int lane = threadIdx.x & 63;
    int beg = rowstart[w], end = rowstart[w + 1];
    float a0 = 0.f, a1 = 0.f, b0 = 0.f, b1 = 0.f;
    int j = beg;
    for (; j + 1 < end; j += 2) {
        int s0 = adj[j], s1 = adj[j + 1];
        uint v0 = xh[(size_t)s0 * 64 + lane];
        uint v1 = xh[(size_t)s1 * 64 + lane];
        a0 += blo(v0); a1 += bhi(v0);
        b0 += blo(v1); b1 += bhi(v1);
    }
    if (j < end) {
        uint v0 = xh[(size_t)adj[j] * 64 + lane];
        a0 += blo(v0); a1 += bhi(v0);
    }
    float inv = 1.0f / fmaxf((float)(end - beg), 1.0f);
    outm[(size_t)w * 64 + lane] = pack2((a0 + b0) * inv, (a1 + b1) * inv);
}

// ---------------------------------------------------------------------------
// fused SAGE linear: out = relu(mean @ Wl^T + bl + xin @ Wr^T)
// bf16 inputs (converted to f32 in LDS), f32 weights/compute, bf16 output
__global__ __launch_bounds__(256)
void k_linear(const ushort* __restrict__ mean, const ushort* __restrict__ xin,
              const float* __restrict__ Wl, const float* __restrict__ bias,
              const float* __restrict__ Wr, ushort* __restrict__ outh)
{
    __shared__ float sWT[32][132];
    __shared__ float sInT[32][36];
    const int tid = threadIdx.x;
    const int row0 = blockIdx.x * 32;
    const int tc = tid & 31, tr = tid >> 5;
    const int c0 = tc * 4, r0 = tr * 4;

    float acc[4][4] = {};

    for (int phase = 0; phase < 2; ++phase) {
        const float*  W  = phase ? Wr : Wl;
        const ushort* In = phase ? xin : mean;
        for (int kb = 0; kb < 128; kb += 32) {
            #pragma unroll
            for (int i = 0; i < 4; ++i) {
                int idx = tid + i * 256;
                int c = idx >> 3, kq = (idx & 7) << 2;
                float4 w = *reinterpret_cast<const float4*>(W + c * DD + kb + kq);
                sWT[kq + 0][c] = w.x; sWT[kq + 1][c] = w.y;
                sWT[kq + 2][c] = w.z; sWT[kq + 3][c] = w.w;
            }
            {
                int r = tid >> 3, kq = (tid & 7) << 2;
                uint2 v = *reinterpret_cast<const uint2*>(
                    In + (size_t)(row0 + r) * DD + kb + kq);
                sInT[kq + 0][r] = blo(v.x); sInT[kq + 1][r] = bhi(v.x);
                sInT[kq + 2][r] = blo(v.y); sInT[kq + 3][r] = bhi(v.y);
            }
            __syncthreads();
            #pragma unroll
            for (int kk = 0; kk < 32; ++kk) {
                float4 w  = *reinterpret_cast<const float4*>(&sWT[kk][c0]);
                float4 xi = *reinterpret_cast<const float4*>(&sInT[kk][r0]);
                const float xv[4] = {xi.x, xi.y, xi.z, xi.w};
                const float wv[4] = {w.x, w.y, w.z, w.w};
                #pragma unroll
                for (int i = 0; i < 4; ++i)
                    #pragma unroll
                    for (int j = 0; j < 4; ++j)
                        acc[i][j] += xv[i] * wv[j];
            }
            __syncthreads();
        }
    }

    float4 b = *reinterpret_cast<const float4*>(bias + c0);
    #pragma unroll
    for (int i = 0; i < 4; ++i) {
        float o0 = fmaxf(acc[i][0] + b.x, 0.0f);
        float o1 = fmaxf(acc[i][1] + b.y, 0.0f);
        float o2 = fmaxf(acc[i][2] + b.z, 0.0f);
        float o3 = fmaxf(acc[i][3] + b.w, 0.0f);
        uint2 p; p.x = pack2(o0, o1); p.y = pack2(o2, o3);
        *reinterpret_cast<uint2*>(outh + (size_t)(row0 + r0 + i) * DD + c0) = p;
    }
}

// ---------------------------------------------------------------------------
// output layer: out = h @ Wout^T + bout   (N x 40), bf16 h, f32 out
__global__ __launch_bounds__(320)
void k_out(const uint* __restrict__ h, const float* __restrict__ Wout,
           const float* __restrict__ bout, float* __restrict__ out)
{
    __shared__ float sW[128][44];
    __shared__ float sH[32][132];
    const int tid = threadIdx.x;
    const int row0 = blockIdx.x * 32;

    #pragma unroll
    for (int i = 0; i < 16; ++i) {
        int idx = tid + i * 320;
        int c = idx >> 7, k = idx & 127;
        sW[k][c] = Wout[idx];
    }
    for (int i = tid; i < 32 * 64; i += 320) {
        int r = i >> 6, kk = (i & 63) * 2;
        uint v = h[(size_t)(row0 + r) * 64 + (i & 63)];
        sH[r][kk] = blo(v); sH[r][kk + 1] = bhi(v);
    }
    __syncthreads();

    const int r = tid / 10, c0 = (tid % 10) * 4;
    float4 b = *reinterpret_cast<const float4*>(bout + c0);
    float4 acc = b;
    #pragma unroll 4
    for (int k = 0; k < 128; ++k) {
        float hv = sH[r][k];
        float4 w = *reinterpret_cast<const float4*>(&sW[k][c0]);
        acc.x += hv * w.x; acc.y += hv * w.y;
        acc.z += hv * w.z; acc.w += hv * w.w;
    }
    *reinterpret_cast<float4*>(out + (size_t)(row0 + r) * CC + c0) = acc;
}

// ---------------------------------------------------------------------------
extern "C" void kernel_launch(void* const* d_in, const int* in_sizes, int n_in,
                              void* d_out, int out_size, void* d_ws, size_t ws_size,
                              hipStream_t stream)
{
    const float* x    = (const float*)d_in[0];
    const int*   ei   = (const int*)d_in[1];
    const float* Wl1  = (const float*)d_in[2];
    const float* bl1  = (const float*)d_in[3];
    const float* Wr1  = (const float*)d_in[4];
    const float* Wl2  = (const float*)d_in[5];
    const float* bl2  = (const float*)d_in[6];
    const float* Wr2  = (const float*)d_in[7];
    const float* Wout = (const float*)d_in[8];
    const float* bout = (const float*)d_in[9];
    float* out = (float*)d_out;

    const int E = in_sizes[1] / 2;
    const int* srcI = ei;        // edge_index[0]
    const int* dstI = ei + E;    // edge_index[1]

    // workspace layout:
    // xh [N*128 bf16] | m [N*128 bf16] | h1 [N*128 bf16] |
    // cnt [N] | rowstart [N+1] | cursor [N] | bsum [NB] | boff [NB] | adj [E]
    ushort* xh = (ushort*)d_ws;
    ushort* m  = xh + (size_t)NN * DD;
    ushort* h1 = m + (size_t)NN * DD;
    int* cnt      = (int*)(h1 + (size_t)NN * DD);
    int* rowstart = cnt + NN;
    int* cursor   = rowstart + NN + 1;
    int* bsum     = cursor + NN;
    int* boff     = bsum + NB;
    int* adj      = boff + NB;

    dim3 b256(256);
    const int aggBlocks = (NN * 64 + 255) / 256;   // one wave per node
    const int n8 = NN * DD / 8;

    // ---- convert x to bf16 + CSR build
    k_cvt<<<(n8 + 255) / 256, b256, 0, stream>>>(x, (uint*)xh, n8);
    hipMemsetAsync(cnt, 0, NN * sizeof(int), stream);
    k_count<<<(E + 255) / 256, b256, 0, stream>>>(dstI, cnt, E);
    k_sumchunk<<<NB, b256, 0, stream>>>(cnt, bsum);
    k_scanb<<<1, dim3(128), 0, stream>>>(bsum, boff, rowstart, E);
    k_scanfinal<<<NB, b256, 0, stream>>>(cnt, boff, rowstart, cursor);
    k_fill<<<(E + 255) / 256, b256, 0, stream>>>(srcI, dstI, cursor, adj, E);

    // ---- layer 1
    k_aggregate<<<aggBlocks, b256, 0, stream>>>(rowstart, adj, (const uint*)xh, (uint*)m);
    k_linear<<<NN / 32, b256, 0, stream>>>(m, xh, Wl1, bl1, Wr1, h1);

    // ---- layer 2 (h2 in-place into m; each block writes only its own rows)
    k_aggregate<<<aggBlocks, b256, 0, stream>>>(rowstart, adj, (const uint*)h1, (uint*)m);
    k_linear<<<NN / 32, b256, 0, stream>>>(m, h1, Wl2, bl2, Wr2, m);

    // ---- classifier head
    k_out<<<NN / 32, dim3(320), 0, stream>>>((const uint*)m, Wout, bout, out);
}

// Round 4
// 444.856 us; speedup vs baseline: 12.8880x; 1.3992x over previous
//
#include <hip/hip_runtime.h>

#define NN 100000
#define DD 128
#define CC 40
#define BSH 9                      // bucket = dst >> 9
#define BSZ 512                    // nodes per bucket
#define NBK ((NN + BSZ - 1) / BSZ) // 196 buckets

typedef unsigned int  uint;
typedef unsigned short ushort;

// bf16 helpers (bit-level, round-to-nearest-even)
__device__ __forceinline__ float blo(uint u) { return __uint_as_float(u << 16); }
__device__ __forceinline__ float bhi(uint u) { return __uint_as_float(u & 0xFFFF0000u); }
__device__ __forceinline__ uint  f2b(float f) {
    uint u = __float_as_uint(f);
    return (u + 0x7FFFu + ((u >> 16) & 1u)) >> 16;
}
__device__ __forceinline__ uint pack2(float lo, float hi) { return f2b(lo) | (f2b(hi) << 16); }

// ---------------------------------------------------------------------------
// x (f32) -> xh (bf16), 8 elems/thread
__global__ __launch_bounds__(256)
void k_cvt(const float* __restrict__ x, uint* __restrict__ xh, int n8) {
    int i = blockIdx.x * 256 + threadIdx.x;
    if (i >= n8) return;
    float4 a = reinterpret_cast<const float4*>(x)[i * 2];
    float4 b = reinterpret_cast<const float4*>(x)[i * 2 + 1];
    uint4 o;
    o.x = pack2(a.x, a.y); o.y = pack2(a.z, a.w);
    o.z = pack2(b.x, b.y); o.w = pack2(b.z, b.w);
    reinterpret_cast<uint4*>(xh)[i] = o;
}

// ---------------------------------------------------------------------------
// bucket histogram: ghist[dst>>BSH] += 1 (LDS-staged)
__global__ __launch_bounds__(256)
void k_hist(const int* __restrict__ dst, int* __restrict__ ghist, int E) {
    __shared__ int h[NBK];
    for (int i = threadIdx.x; i < NBK; i += 256) h[i] = 0;
    __syncthreads();
    int stride = gridDim.x * 256;
    for (int i = blockIdx.x * 256 + threadIdx.x; i < E; i += stride)
        atomicAdd(&h[dst[i] >> BSH], 1);
    __syncthreads();
    for (int i = threadIdx.x; i < NBK; i += 256)
        if (h[i]) atomicAdd(&ghist[i], h[i]);
}

// exclusive scan of the 196 bucket sums (single block)
__global__ __launch_bounds__(256)
void k_scanbk(const int* __restrict__ ghist, int* __restrict__ bucketBase,
              int* __restrict__ bucketCursor, int* __restrict__ rowstart, int E) {
    __shared__ int s[256];
    int t = threadIdx.x;
    int v = (t < NBK) ? ghist[t] : 0;
    s[t] = v; __syncthreads();
    for (int off = 1; off < 256; off <<= 1) {
        int add = (t >= off) ? s[t - off] : 0;
        __syncthreads();
        s[t] += add;
        __syncthreads();
    }
    if (t < NBK) { int ex = s[t] - v; bucketBase[t] = ex; bucketCursor[t] = ex; }
    if (t == 0) { bucketBase[NBK] = E; rowstart[NN] = E; }
}

// partition edges into bucket regions; block-exclusive contiguous runs
__global__ __launch_bounds__(256)
void k_partition(const int* __restrict__ src, const int* __restrict__ dst,
                 int* __restrict__ bucketCursor, uint* __restrict__ tmp, int E) {
    __shared__ int h[NBK];
    __shared__ int cur[NBK];
    int chunk = (E + gridDim.x - 1) / gridDim.x;
    int lo = blockIdx.x * chunk;
    int hi = min(lo + chunk, E);
    for (int i = threadIdx.x; i < NBK; i += 256) h[i] = 0;
    __syncthreads();
    for (int i = lo + threadIdx.x; i < hi; i += 256)
        atomicAdd(&h[dst[i] >> BSH], 1);
    __syncthreads();
    for (int i = threadIdx.x; i < NBK; i += 256) {
        int c = h[i];
        cur[i] = c ? atomicAdd(&bucketCursor[i], c) : 0;
    }
    __syncthreads();
    for (int i = lo + threadIdx.x; i < hi; i += 256) {
        int d = dst[i];
        int pos = atomicAdd(&cur[d >> BSH], 1);
        tmp[pos] = ((uint)(d & (BSZ - 1)) << 17) | (uint)src[i];
    }
}

// per-bucket: LDS histogram + scan -> rowstart; LDS-cursor scatter -> adj
__global__ __launch_bounds__(256)
void k_bucket(const uint* __restrict__ tmp, const int* __restrict__ bucketBase,
              int* __restrict__ rowstart, int* __restrict__ adj) {
    __shared__ int cnt[BSZ];
    __shared__ int cur[BSZ];
    __shared__ int ps[256];
    int b = blockIdx.x, t = threadIdx.x;
    int bb = bucketBase[b], be = bucketBase[b + 1];
    cnt[t] = 0; cnt[t + 256] = 0;
    __syncthreads();
    for (int i = bb + t; i < be; i += 256)
        atomicAdd(&cnt[tmp[i] >> 17], 1);
    __syncthreads();
    int c0 = cnt[2 * t], c1 = cnt[2 * t + 1];
    ps[t] = c0 + c1;
    __syncthreads();
    for (int off = 1; off < 256; off <<= 1) {
        int add = (t >= off) ? ps[t - off] : 0;
        __syncthreads();
        ps[t] += add;
        __syncthreads();
    }
    int ex = ps[t] - (c0 + c1);
    cur[2 * t] = ex; cur[2 * t + 1] = ex + c0;
    int node0 = b * BSZ;
    if (node0 + 2 * t < NN)     rowstart[node0 + 2 * t]     = bb + ex;
    if (node0 + 2 * t + 1 < NN) rowstart[node0 + 2 * t + 1] = bb + ex + c0;
    __syncthreads();
    for (int i = bb + t; i < be; i += 256) {
        uint e = tmp[i];
        int pos = bb + atomicAdd(&cur[e >> 17], 1);
        adj[pos] = (int)(e & 0x1FFFFu);
    }
}

// ---------------------------------------------------------------------------
// gather-aggregate over bf16 rows: one wave/node, 1 uint (2 bf16) per lane
__global__ __launch_bounds__(256)
void k_aggregate(const int* __restrict__ rowstart, const int* __restrict__ adj,
                 const uint* __restrict__ xh, uint* __restrict__ outm) {
    int w = (blockIdx.x * 256 + threadIdx.x) >> 6;   // node id
    if (w >= NN) return;
    int lane = threadIdx.x & 63;
    int beg = rowstart[w], end = rowstart[w + 1];
    float a0 = 0.f, a1 = 0.f, b0 = 0.f, b1 = 0.f;
    float c0 = 0.f, c1 = 0.f, d0 = 0.f, d1 = 0.f;
    int j = beg;
    for (; j + 3 < end; j += 4) {
        uint v0 = xh[(size_t)adj[j]     * 64 + lane];
        uint v1 = xh[(size_t)adj[j + 1] * 64 + lane];
        uint v2 = xh[(size_t)adj[j + 2] * 64 + lane];
        uint v3 = xh[(size_t)adj[j + 3] * 64 + lane];
        a0 += blo(v0); a1 += bhi(v0);
        b0 += blo(v1); b1 += bhi(v1);
        c0 += blo(v2); c1 += bhi(v2);
        d0 += blo(v3); d1 += bhi(v3);
    }
    for (; j < end; ++j) {
        uint v0 = xh[(size_t)adj[j] * 64 + lane];
        a0 += blo(v0); a1 += bhi(v0);
    }
    float inv = 1.0f / fmaxf((float)(end - beg), 1.0f);
    outm[(size_t)w * 64 + lane] =
        pack2((a0 + b0 + c0 + d0) * inv, (a1 + b1 + c1 + d1) * inv);
}

// ---------------------------------------------------------------------------
// fused SAGE linear: out = relu(mean @ Wl^T + bl + xin @ Wr^T)
// bf16 inputs (converted to f32 in LDS), f32 weights/compute, bf16 output
__global__ __launch_bounds__(256)
void k_linear(const ushort* __restrict__ mean, const ushort* __restrict__ xin,
              const float* __restrict__ Wl, const float* __restrict__ bias,
              const float* __restrict__ Wr, ushort* __restrict__ outh)
{
    __shared__ float sWT[32][132];
    __shared__ float sInT[32][36];
    const int tid = threadIdx.x;
    const int row0 = blockIdx.x * 32;
    const int tc = tid & 31, tr = tid >> 5;
    const int c0 = tc * 4, r0 = tr * 4;

    float acc[4][4] = {};

    for (int phase = 0; phase < 2; ++phase) {
        const float*  W  = phase ? Wr : Wl;
        const ushort* In = phase ? xin : mean;
        for (int kb = 0; kb < 128; kb += 32) {
            #pragma unroll
            for (int i = 0; i < 4; ++i) {
                int idx = tid + i * 256;
                int c = idx >> 3, kq = (idx & 7) << 2;
                float4 w = *reinterpret_cast<const float4*>(W + c * DD + kb + kq);
                sWT[kq + 0][c] = w.x; sWT[kq + 1][c] = w.y;
                sWT[kq + 2][c] = w.z; sWT[kq + 3][c] = w.w;
            }
            {
                int r = tid >> 3, kq = (tid & 7) << 2;
                uint2 v = *reinterpret_cast<const uint2*>(
                    In + (size_t)(row0 + r) * DD + kb + kq);
                sInT[kq + 0][r] = blo(v.x); sInT[kq + 1][r] = bhi(v.x);
                sInT[kq + 2][r] = blo(v.y); sInT[kq + 3][r] = bhi(v.y);
            }
            __syncthreads();
            #pragma unroll
            for (int kk = 0; kk < 32; ++kk) {
                float4 w  = *reinterpret_cast<const float4*>(&sWT[kk][c0]);
                float4 xi = *reinterpret_cast<const float4*>(&sInT[kk][r0]);
                const float xv[4] = {xi.x, xi.y, xi.z, xi.w};
                const float wv[4] = {w.x, w.y, w.z, w.w};
                #pragma unroll
                for (int i = 0; i < 4; ++i)
                    #pragma unroll
                    for (int j = 0; j < 4; ++j)
                        acc[i][j] += xv[i] * wv[j];
            }
            __syncthreads();
        }
    }

    float4 b = *reinterpret_cast<const float4*>(bias + c0);
    #pragma unroll
    for (int i = 0; i < 4; ++i) {
        float o0 = fmaxf(acc[i][0] + b.x, 0.0f);
        float o1 = fmaxf(acc[i][1] + b.y, 0.0f);
        float o2 = fmaxf(acc[i][2] + b.z, 0.0f);
        float o3 = fmaxf(acc[i][3] + b.w, 0.0f);
        uint2 p; p.x = pack2(o0, o1); p.y = pack2(o2, o3);
        *reinterpret_cast<uint2*>(outh + (size_t)(row0 + r0 + i) * DD + c0) = p;
    }
}

// ---------------------------------------------------------------------------
// output layer: out = h @ Wout^T + bout   (N x 40), bf16 h, f32 out
__global__ __launch_bounds__(320)
void k_out(const uint* __restrict__ h, const float* __restrict__ Wout,
           const float* __restrict__ bout, float* __restrict__ out)
{
    __shared__ float sW[128][44];
    __shared__ float sH[32][132];
    const int tid = threadIdx.x;
    const int row0 = blockIdx.x * 32;

    #pragma unroll
    for (int i = 0; i < 16; ++i) {
        int idx = tid + i * 320;
        int c = idx >> 7, k = idx & 127;
        sW[k][c] = Wout[idx];
    }
    for (int i = tid; i < 32 * 64; i += 320) {
        int r = i >> 6, kk = (i & 63) * 2;
        uint v = h[(size_t)(row0 + r) * 64 + (i & 63)];
        sH[r][kk] = blo(v); sH[r][kk + 1] = bhi(v);
    }
    __syncthreads();

    const int r = tid / 10, c0 = (tid % 10) * 4;
    float4 b = *reinterpret_cast<const float4*>(bout + c0);
    float4 acc = b;
    #pragma unroll 4
    for (int k = 0; k < 128; ++k) {
        float hv = sH[r][k];
        float4 w = *reinterpret_cast<const float4*>(&sW[k][c0]);
        acc.x += hv * w.x; acc.y += hv * w.y;
        acc.z += hv * w.z; acc.w += hv * w.w;
    }
    *reinterpret_cast<float4*>(out + (size_t)(row0 + r) * CC + c0) = acc;
}

// ---------------------------------------------------------------------------
extern "C" void kernel_launch(void* const* d_in, const int* in_sizes, int n_in,
                              void* d_out, int out_size, void* d_ws, size_t ws_size,
                              hipStream_t stream)
{
    const float* x    = (const float*)d_in[0];
    const int*   ei   = (const int*)d_in[1];
    const float* Wl1  = (const float*)d_in[2];
    const float* bl1  = (const float*)d_in[3];
    const float* Wr1  = (const float*)d_in[4];
    const float* Wl2  = (const float*)d_in[5];
    const float* bl2  = (const float*)d_in[6];
    const float* Wr2  = (const float*)d_in[7];
    const float* Wout = (const float*)d_in[8];
    const float* bout = (const float*)d_in[9];
    float* out = (float*)d_out;

    const int E = in_sizes[1] / 2;
    const int* srcI = ei;        // edge_index[0]
    const int* dstI = ei + E;    // edge_index[1]

    // workspace layout:
    // xh [N*64 uint] | m [N*64] | h1 [N*64] | rowstart [N+1] | adj [E] |
    // tmp [E] | ghist [NBK] | bucketBase [NBK+1] | bucketCursor [NBK]
    ushort* xh = (ushort*)d_ws;
    ushort* m  = xh + (size_t)NN * DD;
    ushort* h1 = m + (size_t)NN * DD;
    int* rowstart     = (int*)(h1 + (size_t)NN * DD);
    int* adj          = rowstart + NN + 1;
    uint* tmp         = (uint*)(adj + E);
    int* ghist        = (int*)(tmp + E);
    int* bucketBase   = ghist + NBK;
    int* bucketCursor = bucketBase + NBK + 1;

    dim3 b256(256);
    const int aggBlocks = (NN * 64 + 255) / 256;   // one wave per node
    const int n8 = NN * DD / 8;

    // ---- convert x to bf16 + CSR build (bucket radix)
    k_cvt<<<(n8 + 255) / 256, b256, 0, stream>>>(x, (uint*)xh, n8);
    hipMemsetAsync(ghist, 0, NBK * sizeof(int), stream);
    k_hist<<<256, b256, 0, stream>>>(dstI, ghist, E);
    k_scanbk<<<1, b256, 0, stream>>>(ghist, bucketBase, bucketCursor, rowstart, E);
    k_partition<<<256, b256, 0, stream>>>(srcI, dstI, bucketCursor, tmp, E);
    k_bucket<<<NBK, b256, 0, stream>>>(tmp, bucketBase, rowstart, adj);

    // ---- layer 1
    k_aggregate<<<aggBlocks, b256, 0, stream>>>(rowstart, adj, (const uint*)xh, (uint*)m);
    k_linear<<<NN / 32, b256, 0, stream>>>(m, xh, Wl1, bl1, Wr1, h1);

    // ---- layer 2 (h2 in-place into m; each block writes only its own rows)
    k_aggregate<<<aggBlocks, b256, 0, stream>>>(rowstart, adj, (const uint*)h1, (uint*)m);
    k_linear<<<NN / 32, b256, 0, stream>>>(m, h1, Wl2, bl2, Wr2, m);

    // ---- classifier head
    k_out<<<NN / 32, dim3(320), 0, stream>>>((const uint*)m, Wout, bout, out);
}

// Round 5
// 324.049 us; speedup vs baseline: 17.6928x; 1.3728x over previous
//
#include <hip/hip_runtime.h>

#define NN 100000
#define DD 128
#define CC 40
#define BSH 9                      // bucket = dst >> 9
#define BSZ 512                    // nodes per bucket
#define NBK ((NN + BSZ - 1) / BSZ) // 196 buckets

typedef unsigned int  uint;
typedef unsigned short ushort;

typedef __attribute__((ext_vector_type(8))) short  s16x8;   // 8 bf16 (4 VGPRs)
typedef __attribute__((ext_vector_type(4))) float  f32x4;
typedef __attribute__((ext_vector_type(4))) uint   u32x4;

// bf16 helpers (bit-level, round-to-nearest-even)
__device__ __forceinline__ float blo(uint u) { return __uint_as_float(u << 16); }
__device__ __forceinline__ float bhi(uint u) { return __uint_as_float(u & 0xFFFF0000u); }
__device__ __forceinline__ uint  f2b(float f) {
    uint u = __float_as_uint(f);
    return (u + 0x7FFFu + ((u >> 16) & 1u)) >> 16;
}
__device__ __forceinline__ uint pack2(float lo, float hi) { return f2b(lo) | (f2b(hi) << 16); }

// ---------------------------------------------------------------------------
// x (f32) -> xh (bf16), 8 elems/thread
__global__ __launch_bounds__(256)
void k_cvt(const float* __restrict__ x, uint* __restrict__ xh, int n8) {
    int i = blockIdx.x * 256 + threadIdx.x;
    if (i >= n8) return;
    float4 a = reinterpret_cast<const float4*>(x)[i * 2];
    float4 b = reinterpret_cast<const float4*>(x)[i * 2 + 1];
    uint4 o;
    o.x = pack2(a.x, a.y); o.y = pack2(a.z, a.w);
    o.z = pack2(b.x, b.y); o.w = pack2(b.z, b.w);
    reinterpret_cast<uint4*>(xh)[i] = o;
}

// ---------------------------------------------------------------------------
// pack [Wl;Wr] (f32, row-major [N][K]) into bf16 MFMA B-operand fragments.
// pB layout: frag index r = (kb*8+nt)*64 + lane; element j (0..7) = bf16 of
// B[kb*32+(lane>>4)*8+j][nt*16+(lane&15)], B[k][n] = k<128 ? Wl[n][k] : Wr[n][k-128]
__global__ __launch_bounds__(256)
void k_prepw(const float* __restrict__ Wl1, const float* __restrict__ Wr1,
             const float* __restrict__ Wl2, const float* __restrict__ Wr2,
             uint* __restrict__ pB1, uint* __restrict__ pB2) {
    int t = blockIdx.x * 256 + threadIdx.x;   // 0..8191
    int layer = t >> 12;
    int r = t & 4095;
    int kb = r >> 9, nt = (r >> 6) & 7, l = r & 63;
    int n  = nt * 16 + (l & 15);
    int k0 = kb * 32 + ((l >> 4) << 3);       // chunk never straddles 128
    const float* W = (k0 < 128) ? (layer ? Wl2 : Wl1) : (layer ? Wr2 : Wr1);
    int kk = k0 & 127;
    float4 wa = *reinterpret_cast<const float4*>(W + n * DD + kk);
    float4 wb = *reinterpret_cast<const float4*>(W + n * DD + kk + 4);
    uint4 o;
    o.x = pack2(wa.x, wa.y); o.y = pack2(wa.z, wa.w);
    o.z = pack2(wb.x, wb.y); o.w = pack2(wb.z, wb.w);
    uint* pB = layer ? pB2 : pB1;
    *reinterpret_cast<uint4*>(pB + (size_t)r * 4) = o;
}

// ---------------------------------------------------------------------------
// bucket histogram: ghist[dst>>BSH] += 1 (LDS-staged)
__global__ __launch_bounds__(256)
void k_hist(const int* __restrict__ dst, int* __restrict__ ghist, int E) {
    __shared__ int h[NBK];
    for (int i = threadIdx.x; i < NBK; i += 256) h[i] = 0;
    __syncthreads();
    int stride = gridDim.x * 256;
    for (int i = blockIdx.x * 256 + threadIdx.x; i < E; i += stride)
        atomicAdd(&h[dst[i] >> BSH], 1);
    __syncthreads();
    for (int i = threadIdx.x; i < NBK; i += 256)
        if (h[i]) atomicAdd(&ghist[i], h[i]);
}

// exclusive scan of the 196 bucket sums (single block)
__global__ __launch_bounds__(256)
void k_scanbk(const int* __restrict__ ghist, int* __restrict__ bucketBase,
              int* __restrict__ bucketCursor, int* __restrict__ rowstart, int E) {
    __shared__ int s[256];
    int t = threadIdx.x;
    int v = (t < NBK) ? ghist[t] : 0;
    s[t] = v; __syncthreads();
    for (int off = 1; off < 256; off <<= 1) {
        int add = (t >= off) ? s[t - off] : 0;
        __syncthreads();
        s[t] += add;
        __syncthreads();
    }
    if (t < NBK) { int ex = s[t] - v; bucketBase[t] = ex; bucketCursor[t] = ex; }
    if (t == 0) { bucketBase[NBK] = E; rowstart[NN] = E; }
}

// partition edges into bucket regions; block-exclusive contiguous runs
__global__ __launch_bounds__(256)
void k_partition(const int* __restrict__ src, const int* __restrict__ dst,
                 int* __restrict__ bucketCursor, uint* __restrict__ tmp, int E) {
    __shared__ int h[NBK];
    __shared__ int cur[NBK];
    int chunk = (E + gridDim.x - 1) / gridDim.x;
    int lo = blockIdx.x * chunk;
    int hi = min(lo + chunk, E);
    for (int i = threadIdx.x; i < NBK; i += 256) h[i] = 0;
    __syncthreads();
    for (int i = lo + threadIdx.x; i < hi; i += 256)
        atomicAdd(&h[dst[i] >> BSH], 1);
    __syncthreads();
    for (int i = threadIdx.x; i < NBK; i += 256) {
        int c = h[i];
        cur[i] = c ? atomicAdd(&bucketCursor[i], c) : 0;
    }
    __syncthreads();
    for (int i = lo + threadIdx.x; i < hi; i += 256) {
        int d = dst[i];
        int pos = atomicAdd(&cur[d >> BSH], 1);
        tmp[pos] = ((uint)(d & (BSZ - 1)) << 17) | (uint)src[i];
    }
}

// per-bucket: LDS histogram + scan -> rowstart; LDS-cursor scatter -> adj
__global__ __launch_bounds__(256)
void k_bucket(const uint* __restrict__ tmp, const int* __restrict__ bucketBase,
              int* __restrict__ rowstart, int* __restrict__ adj) {
    __shared__ int cnt[BSZ];
    __shared__ int cur[BSZ];
    __shared__ int ps[256];
    int b = blockIdx.x, t = threadIdx.x;
    int bb = bucketBase[b], be = bucketBase[b + 1];
    cnt[t] = 0; cnt[t + 256] = 0;
    __syncthreads();
    for (int i = bb + t; i < be; i += 256)
        atomicAdd(&cnt[tmp[i] >> 17], 1);
    __syncthreads();
    int c0 = cnt[2 * t], c1 = cnt[2 * t + 1];
    ps[t] = c0 + c1;
    __syncthreads();
    for (int off = 1; off < 256; off <<= 1) {
        int add = (t >= off) ? ps[t - off] : 0;
        __syncthreads();
        ps[t] += add;
        __syncthreads();
    }
    int ex = ps[t] - (c0 + c1);
    cur[2 * t] = ex; cur[2 * t + 1] = ex + c0;
    int node0 = b * BSZ;
    if (node0 + 2 * t < NN)     rowstart[node0 + 2 * t]     = bb + ex;
    if (node0 + 2 * t + 1 < NN) rowstart[node0 + 2 * t + 1] = bb + ex + c0;
    __syncthreads();
    for (int i = bb + t; i < be; i += 256) {
        uint e = tmp[i];
        int pos = bb + atomicAdd(&cur[e >> 17], 1);
        adj[pos] = (int)(e & 0x1FFFFu);
    }
}

// ---------------------------------------------------------------------------
// gather-aggregate over bf16 rows: one wave/node, 1 uint (2 bf16) per lane
__global__ __launch_bounds__(256)
void k_aggregate(const int* __restrict__ rowstart, const int* __restrict__ adj,
                 const uint* __restrict__ xh, uint* __restrict__ outm) {
    int w = (blockIdx.x * 256 + threadIdx.x) >> 6;   // node id
    if (w >= NN) return;
    int lane = threadIdx.x & 63;
    int beg = rowstart[w], end = rowstart[w + 1];
    float a0 = 0.f, a1 = 0.f, b0 = 0.f, b1 = 0.f;
    float c0 = 0.f, c1 = 0.f, d0 = 0.f, d1 = 0.f;
    int j = beg;
    for (; j + 3 < end; j += 4) {
        uint v0 = xh[(size_t)adj[j]     * 64 + lane];
        uint v1 = xh[(size_t)adj[j + 1] * 64 + lane];
        uint v2 = xh[(size_t)adj[j + 2] * 64 + lane];
        uint v3 = xh[(size_t)adj[j + 3] * 64 + lane];
        a0 += blo(v0); a1 += bhi(v0);
        b0 += blo(v1); b1 += bhi(v1);
        c0 += blo(v2); c1 += bhi(v2);
        d0 += blo(v3); d1 += bhi(v3);
    }
    for (; j < end; ++j) {
        uint v0 = xh[(size_t)adj[j] * 64 + lane];
        a0 += blo(v0); a1 += bhi(v0);
    }
    float inv = 1.0f / fmaxf((float)(end - beg), 1.0f);
    outm[(size_t)w * 64 + lane] =
        pack2((a0 + b0 + c0 + d0) * inv, (a1 + b1 + c1 + d1) * inv);
}

// ---------------------------------------------------------------------------
// MFMA fused SAGE linear: out = relu([mean|xin] @ packedW + bias), bf16 in/out
// block: 128 rows x 128 cols, 4 waves (32 rows each), B (64KB) staged in LDS
__global__ __launch_bounds__(256)
void k_linear(const ushort* __restrict__ mean, const ushort* __restrict__ xin,
              const uint* __restrict__ pB, const float* __restrict__ bias,
              ushort* __restrict__ outh)
{
    __shared__ u32x4 sB[4096];   // 64 KB: [kb][nt][lane] 16B frags
    const int tid = threadIdx.x;
    const u32x4* pBv = reinterpret_cast<const u32x4*>(pB);
    #pragma unroll
    for (int i = 0; i < 16; ++i)
        sB[tid + i * 256] = pBv[tid + i * 256];

    const int w = tid >> 6, l = tid & 63;
    const int fq = l >> 4, fr = l & 15;
    const int rbase = blockIdx.x * 128 + w * 32;   // wave-exclusive 32 rows

    f32x4 acc[2][8] = {};
    __syncthreads();

    #pragma unroll
    for (int kb = 0; kb < 8; ++kb) {
        const ushort* In = (kb < 4) ? mean : xin;
        const int ko = (kb & 3) * 32 + fq * 8;
        s16x8 a0 = __builtin_bit_cast(s16x8,
            *reinterpret_cast<const u32x4*>(In + (size_t)(rbase + fr) * DD + ko));
        s16x8 a1 = __builtin_bit_cast(s16x8,
            *reinterpret_cast<const u32x4*>(In + (size_t)(rbase + 16 + fr) * DD + ko));
        #pragma unroll
        for (int nt = 0; nt < 8; ++nt) {
            s16x8 b = __builtin_bit_cast(s16x8, sB[(kb * 8 + nt) * 64 + l]);
            acc[0][nt] = __builtin_amdgcn_mfma_f32_16x16x32_bf16(a0, b, acc[0][nt], 0, 0, 0);
            acc[1][nt] = __builtin_amdgcn_mfma_f32_16x16x32_bf16(a1, b, acc[1][nt], 0, 0, 0);
        }
    }

    // epilogue: bias + relu + bf16 pack; D: col = fr (per nt), row = fq*4+reg
    #pragma unroll
    for (int nt = 0; nt < 8; ++nt) {
        float bn = bias[nt * 16 + fr];
        #pragma unroll
        for (int m = 0; m < 2; ++m) {
            int row = rbase + m * 16 + fq * 4;
            #pragma unroll
            for (int reg = 0; reg < 4; ++reg) {
                int r = row + reg;
                if (r < NN) {
                    float o = fmaxf(acc[m][nt][reg] + bn, 0.0f);
                    outh[(size_t)r * DD + nt * 16 + fr] = (ushort)f2b(o);
                }
            }
        }
    }
}

// ---------------------------------------------------------------------------
// output layer: out = h @ Wout^T + bout   (N x 40), bf16 h, f32 out
__global__ __launch_bounds__(320)
void k_out(const uint* __restrict__ h, const float* __restrict__ Wout,
           const float* __restrict__ bout, float* __restrict__ out)
{
    __shared__ float sW[128][44];
    __shared__ float sH[32][132];
    const int tid = threadIdx.x;
    const int row0 = blockIdx.x * 32;

    #pragma unroll
    for (int i = 0; i < 16; ++i) {
        int idx = tid + i * 320;
        int c = idx >> 7, k = idx & 127;
        sW[k][c] = Wout[idx];
    }
    for (int i = tid; i < 32 * 64; i += 320) {
        int r = i >> 6, kk = (i & 63) * 2;
        uint v = h[(size_t)(row0 + r) * 64 + (i & 63)];
        sH[r][kk] = blo(v); sH[r][kk + 1] = bhi(v);
    }
    __syncthreads();

    const int r = tid / 10, c0 = (tid % 10) * 4;
    float4 b = *reinterpret_cast<const float4*>(bout + c0);
    float4 acc = b;
    #pragma unroll 4
    for (int k = 0; k < 128; ++k) {
        float hv = sH[r][k];
        float4 w = *reinterpret_cast<const float4*>(&sW[k][c0]);
        acc.x += hv * w.x; acc.y += hv * w.y;
        acc.z += hv * w.z; acc.w += hv * w.w;
    }
    *reinterpret_cast<float4*>(out + (size_t)(row0 + r) * CC + c0) = acc;
}

// ---------------------------------------------------------------------------
extern "C" void kernel_launch(void* const* d_in, const int* in_sizes, int n_in,
                              void* d_out, int out_size, void* d_ws, size_t ws_size,
                              hipStream_t stream)
{
    const float* x    = (const float*)d_in[0];
    const int*   ei   = (const int*)d_in[1];
    const float* Wl1  = (const float*)d_in[2];
    const float* bl1  = (const float*)d_in[3];
    const float* Wr1  = (const float*)d_in[4];
    const float* Wl2  = (const float*)d_in[5];
    const float* bl2  = (const float*)d_in[6];
    const float* Wr2  = (const float*)d_in[7];
    const float* Wout = (const float*)d_in[8];
    const float* bout = (const float*)d_in[9];
    float* out = (float*)d_out;

    const int E = in_sizes[1] / 2;
    const int* srcI = ei;        // edge_index[0]
    const int* dstI = ei + E;    // edge_index[1]

    // workspace layout:
    // xh [N*64 uint] | m [N*64] | h1 [N*64] | rowstart [N+1] | adj [E] |
    // tmp [E] | ghist [NBK] | bucketBase [NBK+1] | bucketCursor [NBK] |
    // (16B-align) pB1 [16384 uint] | pB2 [16384 uint]
    ushort* xh = (ushort*)d_ws;
    ushort* m  = xh + (size_t)NN * DD;
    ushort* h1 = m + (size_t)NN * DD;
    int* rowstart     = (int*)(h1 + (size_t)NN * DD);
    int* adj          = rowstart + NN + 1;
    uint* tmp         = (uint*)(adj + E);
    int* ghist        = (int*)(tmp + E);
    int* bucketBase   = ghist + NBK;
    int* bucketCursor = bucketBase + NBK + 1;
    uintptr_t pb = ((uintptr_t)(bucketCursor + NBK) + 15) & ~(uintptr_t)15;
    uint* pB1 = (uint*)pb;
    uint* pB2 = pB1 + 16384;

    dim3 b256(256);
    const int aggBlocks = (NN * 64 + 255) / 256;   // one wave per node
    const int linBlocks = (NN + 127) / 128;
    const int n8 = NN * DD / 8;

    // ---- convert x to bf16, pack weights, CSR build (bucket radix)
    k_cvt<<<(n8 + 255) / 256, b256, 0, stream>>>(x, (uint*)xh, n8);
    k_prepw<<<32, b256, 0, stream>>>(Wl1, Wr1, Wl2, Wr2, pB1, pB2);
    hipMemsetAsync(ghist, 0, NBK * sizeof(int), stream);
    k_hist<<<256, b256, 0, stream>>>(dstI, ghist, E);
    k_scanbk<<<1, b256, 0, stream>>>(ghist, bucketBase, bucketCursor, rowstart, E);
    k_partition<<<256, b256, 0, stream>>>(srcI, dstI, bucketCursor, tmp, E);
    k_bucket<<<NBK, b256, 0, stream>>>(tmp, bucketBase, rowstart, adj);

    // ---- layer 1
    k_aggregate<<<aggBlocks, b256, 0, stream>>>(rowstart, adj, (const uint*)xh, (uint*)m);
    k_linear<<<linBlocks, b256, 0, stream>>>(m, xh, pB1, bl1, h1);

    // ---- layer 2 (h2 in-place into m; each wave reads/writes only its rows)
    k_aggregate<<<aggBlocks, b256, 0, stream>>>(rowstart, adj, (const uint*)h1, (uint*)m);
    k_linear<<<linBlocks, b256, 0, stream>>>(m, h1, pB2, bl2, m);

    // ---- classifier head
    k_out<<<NN / 32, dim3(320), 0, stream>>>((const uint*)m, Wout, bout, out);
}

// Round 6
// 295.261 us; speedup vs baseline: 19.4178x; 1.0975x over previous
//
#include <hip/hip_runtime.h>

#define NN 100000
#define DD 128
#define CC 40
#define BSH 9                      // bucket = dst >> 9
#define BSZ 512                    // nodes per bucket
#define NBK ((NN + BSZ - 1) / BSZ) // 196 buckets

typedef unsigned int  uint;
typedef unsigned short ushort;

typedef __attribute__((ext_vector_type(8))) short  s16x8;   // 8 bf16 (4 VGPRs)
typedef __attribute__((ext_vector_type(4))) float  f32x4;
typedef __attribute__((ext_vector_type(4))) uint   u32x4;

// bf16 helpers (bit-level, round-to-nearest-even)
__device__ __forceinline__ float blo(uint u) { return __uint_as_float(u << 16); }
__device__ __forceinline__ float bhi(uint u) { return __uint_as_float(u & 0xFFFF0000u); }
__device__ __forceinline__ uint  f2b(float f) {
    uint u = __float_as_uint(f);
    return (u + 0x7FFFu + ((u >> 16) & 1u)) >> 16;
}
__device__ __forceinline__ uint pack2(float lo, float hi) { return f2b(lo) | (f2b(hi) << 16); }

// ---------------------------------------------------------------------------
// x (f32) -> xh (bf16), 8 elems/thread
__global__ __launch_bounds__(256)
void k_cvt(const float* __restrict__ x, uint* __restrict__ xh, int n8) {
    int i = blockIdx.x * 256 + threadIdx.x;
    if (i >= n8) return;
    float4 a = reinterpret_cast<const float4*>(x)[i * 2];
    float4 b = reinterpret_cast<const float4*>(x)[i * 2 + 1];
    uint4 o;
    o.x = pack2(a.x, a.y); o.y = pack2(a.z, a.w);
    o.z = pack2(b.x, b.y); o.w = pack2(b.z, b.w);
    reinterpret_cast<uint4*>(xh)[i] = o;
}

// zero the dummy source row NN of xh and h1 (dummy adj slots point here)
__global__ __launch_bounds__(64)
void k_zrow(uint* __restrict__ xh, uint* __restrict__ h1) {
    int t = threadIdx.x;
    xh[(size_t)NN * 64 + t] = 0;
    h1[(size_t)NN * 64 + t] = 0;
}

// ---------------------------------------------------------------------------
// pack [Wl;Wr] (f32, row-major [N][K]) into bf16 MFMA B-operand fragments.
__global__ __launch_bounds__(256)
void k_prepw(const float* __restrict__ Wl1, const float* __restrict__ Wr1,
             const float* __restrict__ Wl2, const float* __restrict__ Wr2,
             uint* __restrict__ pB1, uint* __restrict__ pB2) {
    int t = blockIdx.x * 256 + threadIdx.x;   // 0..8191
    int layer = t >> 12;
    int r = t & 4095;
    int kb = r >> 9, nt = (r >> 6) & 7, l = r & 63;
    int n  = nt * 16 + (l & 15);
    int k0 = kb * 32 + ((l >> 4) << 3);       // chunk never straddles 128
    const float* W = (k0 < 128) ? (layer ? Wl2 : Wl1) : (layer ? Wr2 : Wr1);
    int kk = k0 & 127;
    float4 wa = *reinterpret_cast<const float4*>(W + n * DD + kk);
    float4 wb = *reinterpret_cast<const float4*>(W + n * DD + kk + 4);
    uint4 o;
    o.x = pack2(wa.x, wa.y); o.y = pack2(wa.z, wa.w);
    o.z = pack2(wb.x, wb.y); o.w = pack2(wb.z, wb.w);
    uint* pB = layer ? pB2 : pB1;
    *reinterpret_cast<uint4*>(pB + (size_t)r * 4) = o;
}

// ---------------------------------------------------------------------------
// bucket histogram: ghist[dst>>BSH] += 1 (LDS-staged)
__global__ __launch_bounds__(256)
void k_hist(const int* __restrict__ dst, int* __restrict__ ghist, int E) {
    __shared__ int h[NBK];
    for (int i = threadIdx.x; i < NBK; i += 256) h[i] = 0;
    __syncthreads();
    int stride = gridDim.x * 256;
    for (int i = blockIdx.x * 256 + threadIdx.x; i < E; i += stride)
        atomicAdd(&h[dst[i] >> BSH], 1);
    __syncthreads();
    for (int i = threadIdx.x; i < NBK; i += 256)
        if (h[i]) atomicAdd(&ghist[i], h[i]);
}

// exclusive scans of bucket sums: exact (for tmp) and padded (for adj)
__global__ __launch_bounds__(256)
void k_scanbk(const int* __restrict__ ghist, int* __restrict__ bucketBase,
              int* __restrict__ bucketCursor, int* __restrict__ basePad, int E) {
    __shared__ int s[256], p[256];
    int t = threadIdx.x;
    int v  = (t < NBK) ? ghist[t] : 0;
    int vp = (t < NBK) ? (((v + 3) & ~3) + 3 * BSZ) : 0;   // worst-case pad
    s[t] = v; p[t] = vp; __syncthreads();
    for (int off = 1; off < 256; off <<= 1) {
        int a = (t >= off) ? s[t - off] : 0;
        int b = (t >= off) ? p[t - off] : 0;
        __syncthreads();
        s[t] += a; p[t] += b;
        __syncthreads();
    }
    if (t < NBK) {
        int exE = s[t] - v;
        bucketBase[t] = exE; bucketCursor[t] = exE;
        basePad[t] = p[t] - vp;                            // 4-aligned
    }
    if (t == 0) bucketBase[NBK] = E;
}

// partition edges into bucket regions; block-exclusive contiguous runs
__global__ __launch_bounds__(256)
void k_partition(const int* __restrict__ src, const int* __restrict__ dst,
                 int* __restrict__ bucketCursor, uint* __restrict__ tmp, int E) {
    __shared__ int h[NBK];
    __shared__ int cur[NBK];
    int chunk = (E + gridDim.x - 1) / gridDim.x;
    int lo = blockIdx.x * chunk;
    int hi = min(lo + chunk, E);
    for (int i = threadIdx.x; i < NBK; i += 256) h[i] = 0;
    __syncthreads();
    for (int i = lo + threadIdx.x; i < hi; i += 256)
        atomicAdd(&h[dst[i] >> BSH], 1);
    __syncthreads();
    for (int i = threadIdx.x; i < NBK; i += 256) {
        int c = h[i];
        cur[i] = c ? atomicAdd(&bucketCursor[i], c) : 0;
    }
    __syncthreads();
    for (int i = lo + threadIdx.x; i < hi; i += 256) {
        int d = dst[i];
        int pos = atomicAdd(&cur[d >> BSH], 1);
        tmp[pos] = ((uint)(d & (BSZ - 1)) << 17) | (uint)src[i];
    }
}

// per-bucket: LDS hist + padded scan -> rowinfo{start,cnt}; scatter; dummy fill
__global__ __launch_bounds__(256)
void k_bucket(const uint* __restrict__ tmp, const int* __restrict__ bucketBase,
              const int* __restrict__ basePad, int2* __restrict__ rowinfo,
              int* __restrict__ adj) {
    __shared__ int cnt[BSZ];
    __shared__ int cur[BSZ];
    __shared__ int ps[256];
    int b = blockIdx.x, t = threadIdx.x;
    int bbE = bucketBase[b], beE = bucketBase[b + 1];
    int bbP = basePad[b];
    cnt[t] = 0; cnt[t + 256] = 0;
    __syncthreads();
    for (int i = bbE + t; i < beE; i += 256)
        atomicAdd(&cnt[tmp[i] >> 17], 1);
    __syncthreads();
    int c0 = cnt[2 * t], c1 = cnt[2 * t + 1];
    int p0 = (c0 + 3) & ~3, p1 = (c1 + 3) & ~3;
    ps[t] = p0 + p1;
    __syncthreads();
    for (int off = 1; off < 256; off <<= 1) {
        int add = (t >= off) ? ps[t - off] : 0;
        __syncthreads();
        ps[t] += add;
        __syncthreads();
    }
    int ex = ps[t] - (p0 + p1);
    cur[2 * t] = ex; cur[2 * t + 1] = ex + p0;
    int node0 = b * BSZ;
    if (node0 + 2 * t < NN)     rowinfo[node0 + 2 * t]     = make_int2(bbP + ex, c0);
    if (node0 + 2 * t + 1 < NN) rowinfo[node0 + 2 * t + 1] = make_int2(bbP + ex + p0, c1);
    __syncthreads();
    for (int i = bbE + t; i < beE; i += 256) {
        uint e = tmp[i];
        int pos = bbP + atomicAdd(&cur[e >> 17], 1);
        adj[pos] = (int)(e & 0x1FFFFu);
    }
    __syncthreads();
    // dummy slots -> zero row NN
    for (int q = c0; q < p0; ++q) adj[bbP + ex + q] = NN;
    int ex1 = ex + p0;
    for (int q = c1; q < p1; ++q) adj[bbP + ex1 + q] = NN;
}

// ---------------------------------------------------------------------------
// gather-aggregate: one wave/node, rows padded to x4 -> dwordx4 adj loads,
// 32-bit offset gathers, no tail branches
__global__ __launch_bounds__(256)
void k_aggregate(const int2* __restrict__ rowinfo, const int* __restrict__ adj,
                 const uint* __restrict__ xh, uint* __restrict__ outm) {
    int w = (blockIdx.x * 256 + threadIdx.x) >> 6;   // node id
    if (w >= NN) return;
    int lane = threadIdx.x & 63;
    int2 ri = rowinfo[w];
    int beg = ri.x, n = ri.y;
    int end = beg + ((n + 3) & ~3);
    float s0 = 0.f, s1 = 0.f, s2 = 0.f, s3 = 0.f;
    float s4 = 0.f, s5 = 0.f, s6 = 0.f, s7 = 0.f;
    #pragma unroll 2
    for (int j = beg; j < end; j += 4) {
        int4 nb = *reinterpret_cast<const int4*>(adj + j);   // 16B-aligned
        uint v0 = xh[(uint)(nb.x * 64 + lane)];
        uint v1 = xh[(uint)(nb.y * 64 + lane)];
        uint v2 = xh[(uint)(nb.z * 64 + lane)];
        uint v3 = xh[(uint)(nb.w * 64 + lane)];
        s0 += blo(v0); s1 += bhi(v0);
        s2 += blo(v1); s3 += bhi(v1);
        s4 += blo(v2); s5 += bhi(v2);
        s6 += blo(v3); s7 += bhi(v3);
    }
    float inv = 1.0f / fmaxf((float)n, 1.0f);
    outm[(uint)(w * 64 + lane)] = pack2((s0 + s2 + s4 + s6) * inv,
                                        (s1 + s3 + s5 + s7) * inv);
}

// ---------------------------------------------------------------------------
// MFMA fused SAGE linear: out = relu([mean|xin] @ packedW + bias), bf16 in/out
__global__ __launch_bounds__(256)
void k_linear(const ushort* __restrict__ mean, const ushort* __restrict__ xin,
              const uint* __restrict__ pB, const float* __restrict__ bias,
              ushort* __restrict__ outh)
{
    __shared__ u32x4 sB[4096];   // 64 KB: [kb][nt][lane] 16B frags
    const int tid = threadIdx.x;
    const u32x4* pBv = reinterpret_cast<const u32x4*>(pB);
    #pragma unroll
    for (int i = 0; i < 16; ++i)
        sB[tid + i * 256] = pBv[tid + i * 256];

    const int w = tid >> 6, l = tid & 63;
    const int fq = l >> 4, fr = l & 15;
    const int rbase = blockIdx.x * 128 + w * 32;   // wave-exclusive 32 rows

    f32x4 acc[2][8] = {};
    __syncthreads();

    #pragma unroll
    for (int kb = 0; kb < 8; ++kb) {
        const ushort* In = (kb < 4) ? mean : xin;
        const int ko = (kb & 3) * 32 + fq * 8;
        s16x8 a0 = __builtin_bit_cast(s16x8,
            *reinterpret_cast<const u32x4*>(In + (size_t)(rbase + fr) * DD + ko));
        s16x8 a1 = __builtin_bit_cast(s16x8,
            *reinterpret_cast<const u32x4*>(In + (size_t)(rbase + 16 + fr) * DD + ko));
        #pragma unroll
        for (int nt = 0; nt < 8; ++nt) {
            s16x8 b = __builtin_bit_cast(s16x8, sB[(kb * 8 + nt) * 64 + l]);
            acc[0][nt] = __builtin_amdgcn_mfma_f32_16x16x32_bf16(a0, b, acc[0][nt], 0, 0, 0);
            acc[1][nt] = __builtin_amdgcn_mfma_f32_16x16x32_bf16(a1, b, acc[1][nt], 0, 0, 0);
        }
    }

    // epilogue: bias + relu + bf16 pack; D: col = fr (per nt), row = fq*4+reg
    #pragma unroll
    for (int nt = 0; nt < 8; ++nt) {
        float bn = bias[nt * 16 + fr];
        #pragma unroll
        for (int m = 0; m < 2; ++m) {
            int row = rbase + m * 16 + fq * 4;
            #pragma unroll
            for (int reg = 0; reg < 4; ++reg) {
                int r = row + reg;
                if (r < NN) {
                    float o = fmaxf(acc[m][nt][reg] + bn, 0.0f);
                    outh[(size_t)r * DD + nt * 16 + fr] = (ushort)f2b(o);
                }
            }
        }
    }
}

// ---------------------------------------------------------------------------
// output layer: out = h @ Wout^T + bout   (N x 40), bf16 h, f32 out
__global__ __launch_bounds__(320)
void k_out(const uint* __restrict__ h, const float* __restrict__ Wout,
           const float* __restrict__ bout, float* __restrict__ out)
{
    __shared__ float sW[128][44];
    __shared__ float sH[32][132];
    const int tid = threadIdx.x;
    const int row0 = blockIdx.x * 32;

    #pragma unroll
    for (int i = 0; i < 16; ++i) {
        int idx = tid + i * 320;
        int c = idx >> 7, k = idx & 127;
        sW[k][c] = Wout[idx];
    }
    for (int i = tid; i < 32 * 64; i += 320) {
        int r = i >> 6, kk = (i & 63) * 2;
        uint v = h[(size_t)(row0 + r) * 64 + (i & 63)];
        sH[r][kk] = blo(v); sH[r][kk + 1] = bhi(v);
    }
    __syncthreads();

    const int r = tid / 10, c0 = (tid % 10) * 4;
    float4 b = *reinterpret_cast<const float4*>(bout + c0);
    float4 acc = b;
    #pragma unroll 4
    for (int k = 0; k < 128; ++k) {
        float hv = sH[r][k];
        float4 w = *reinterpret_cast<const float4*>(&sW[k][c0]);
        acc.x += hv * w.x; acc.y += hv * w.y;
        acc.z += hv * w.z; acc.w += hv * w.w;
    }
    *reinterpret_cast<float4*>(out + (size_t)(row0 + r) * CC + c0) = acc;
}

// ---------------------------------------------------------------------------
extern "C" void kernel_launch(void* const* d_in, const int* in_sizes, int n_in,
                              void* d_out, int out_size, void* d_ws, size_t ws_size,
                              hipStream_t stream)
{
    const float* x    = (const float*)d_in[0];
    const int*   ei   = (const int*)d_in[1];
    const float* Wl1  = (const float*)d_in[2];
    const float* bl1  = (const float*)d_in[3];
    const float* Wr1  = (const float*)d_in[4];
    const float* Wl2  = (const float*)d_in[5];
    const float* bl2  = (const float*)d_in[6];
    const float* Wr2  = (const float*)d_in[7];
    const float* Wout = (const float*)d_in[8];
    const float* bout = (const float*)d_in[9];
    float* out = (float*)d_out;

    const int E = in_sizes[1] / 2;
    const int* srcI = ei;        // edge_index[0]
    const int* dstI = ei + E;    // edge_index[1]

    // workspace layout:
    // xh [(N+1)*64 uint] | m [N*64] | h1 [(N+1)*64] | rowinfo int2[N] |
    // adj [E+310000] | tmp [E] | ghist | bucketBase[NBK+1] | bucketCursor |
    // basePad[NBK+1] | pB1 | pB2
    ushort* xh = (ushort*)d_ws;
    ushort* m  = xh + (size_t)(NN + 1) * DD;
    ushort* h1 = m + (size_t)NN * DD;
    int2* rowinfo = (int2*)(h1 + (size_t)(NN + 1) * DD);
    int* adj          = (int*)(rowinfo + NN);
    uint* tmp         = (uint*)(adj + E + 310000);
    int* ghist        = (int*)(tmp + E);
    int* bucketBase   = ghist + NBK;
    int* bucketCursor = bucketBase + NBK + 1;
    int* basePad      = bucketCursor + NBK;
    uintptr_t pb = ((uintptr_t)(basePad + NBK + 1) + 15) & ~(uintptr_t)15;
    uint* pB1 = (uint*)pb;
    uint* pB2 = pB1 + 16384;

    dim3 b256(256);
    const int aggBlocks = (NN * 64 + 255) / 256;   // one wave per node
    const int linBlocks = (NN + 127) / 128;
    const int n8 = NN * DD / 8;

    // ---- convert x to bf16, zero dummy rows, pack weights, CSR build
    k_cvt<<<(n8 + 255) / 256, b256, 0, stream>>>(x, (uint*)xh, n8);
    k_zrow<<<1, dim3(64), 0, stream>>>((uint*)xh, (uint*)h1);
    k_prepw<<<32, b256, 0, stream>>>(Wl1, Wr1, Wl2, Wr2, pB1, pB2);
    hipMemsetAsync(ghist, 0, NBK * sizeof(int), stream);
    k_hist<<<256, b256, 0, stream>>>(dstI, ghist, E);
    k_scanbk<<<1, b256, 0, stream>>>(ghist, bucketBase, bucketCursor, basePad, E);
    k_partition<<<256, b256, 0, stream>>>(srcI, dstI, bucketCursor, tmp, E);
    k_bucket<<<NBK, b256, 0, stream>>>(tmp, bucketBase, basePad, rowinfo, adj);

    // ---- layer 1
    k_aggregate<<<aggBlocks, b256, 0, stream>>>(rowinfo, adj, (const uint*)xh, (uint*)m);
    k_linear<<<linBlocks, b256, 0, stream>>>(m, xh, pB1, bl1, h1);

    // ---- layer 2 (h2 in-place into m; each wave reads/writes only its rows)
    k_aggregate<<<aggBlocks, b256, 0, stream>>>(rowinfo, adj, (const uint*)h1, (uint*)m);
    k_linear<<<linBlocks, b256, 0, stream>>>(m, h1, pB2, bl2, m);

    // ---- classifier head
    k_out<<<NN / 32, dim3(320), 0, stream>>>((const uint*)m, Wout, bout, out);
}

// Round 7
// 234.806 us; speedup vs baseline: 24.4173x; 1.2575x over previous
//
#include <hip/hip_runtime.h>

#define NN 100000
#define DD 128
#define CC 40
#define BSH 9                      // bucket = dst >> 9
#define BSZ 512                    // nodes per bucket
#define NBK ((NN + BSZ - 1) / BSZ) // 196 buckets
#define CAPT 10240                 // tmp slots per bucket (mean 8163, sigma 90)
#define CAPP (CAPT + 3 * BSZ)      // padded adj slots per bucket = 11776

typedef unsigned int  uint;
typedef unsigned short ushort;

typedef __attribute__((ext_vector_type(8))) short  s16x8;   // 8 bf16 (4 VGPRs)
typedef __attribute__((ext_vector_type(4))) float  f32x4;
typedef __attribute__((ext_vector_type(4))) uint   u32x4;

// bf16 helpers (bit-level, round-to-nearest-even)
__device__ __forceinline__ float blo(uint u) { return __uint_as_float(u << 16); }
__device__ __forceinline__ float bhi(uint u) { return __uint_as_float(u & 0xFFFF0000u); }
__device__ __forceinline__ uint  f2b(float f) {
    uint u = __float_as_uint(f);
    return (u + 0x7FFFu + ((u >> 16) & 1u)) >> 16;
}
__device__ __forceinline__ uint pack2(float lo, float hi) { return f2b(lo) | (f2b(hi) << 16); }

// ---------------------------------------------------------------------------
// x (f32) -> xh (bf16), 8 elems/thread; also zeros dummy row NN of xh and h1
__global__ __launch_bounds__(256)
void k_cvt(const float* __restrict__ x, uint* __restrict__ xh,
           uint* __restrict__ h1, int n8) {
    int i = blockIdx.x * 256 + threadIdx.x;
    if (i < 16) {
        u32x4 z = {0, 0, 0, 0};
        reinterpret_cast<u32x4*>(xh + (size_t)NN * 64)[i] = z;
        reinterpret_cast<u32x4*>(h1 + (size_t)NN * 64)[i] = z;
    }
    if (i >= n8) return;
    float4 a = reinterpret_cast<const float4*>(x)[i * 2];
    float4 b = reinterpret_cast<const float4*>(x)[i * 2 + 1];
    uint4 o;
    o.x = pack2(a.x, a.y); o.y = pack2(a.z, a.w);
    o.z = pack2(b.x, b.y); o.w = pack2(b.z, b.w);
    reinterpret_cast<uint4*>(xh)[i] = o;
}

// ---------------------------------------------------------------------------
// pack weights into bf16 MFMA B-operand fragments.
// layers 1/2: B[k][n] = k<128 ? Wl[n][k] : Wr[n][k-128], frag (kb*8+nt)*64+l
// head:       B[k][n] = n<40 ? Wout[n][k] : 0,           frag (kb*3+nt)*64+l
__global__ __launch_bounds__(256)
void k_prepw(const float* __restrict__ Wl1, const float* __restrict__ Wr1,
             const float* __restrict__ Wl2, const float* __restrict__ Wr2,
             const float* __restrict__ Wout,
             uint* __restrict__ pB1, uint* __restrict__ pB2,
             uint* __restrict__ pBout) {
    int t = blockIdx.x * 256 + threadIdx.x;   // 0..8959
    if (t < 8192) {
        int layer = t >> 12;
        int r = t & 4095;
        int kb = r >> 9, nt = (r >> 6) & 7, l = r & 63;
        int n  = nt * 16 + (l & 15);
        int k0 = kb * 32 + ((l >> 4) << 3);       // chunk never straddles 128
        const float* W = (k0 < 128) ? (layer ? Wl2 : Wl1) : (layer ? Wr2 : Wr1);
        int kk = k0 & 127;
        float4 wa = *reinterpret_cast<const float4*>(W + n * DD + kk);
        float4 wb = *reinterpret_cast<const float4*>(W + n * DD + kk + 4);
        uint4 o;
        o.x = pack2(wa.x, wa.y); o.y = pack2(wa.z, wa.w);
        o.z = pack2(wb.x, wb.y); o.w = pack2(wb.z, wb.w);
        uint* pB = layer ? pB2 : pB1;
        *reinterpret_cast<uint4*>(pB + (size_t)r * 4) = o;
    } else if (t < 8960) {
        int r = t - 8192;                          // 0..767
        int kb = r / 192, rem = r % 192;
        int nt = rem >> 6, l = rem & 63;
        int n  = nt * 16 + (l & 15);
        int k0 = kb * 32 + ((l >> 4) << 3);
        uint4 o = {0, 0, 0, 0};
        if (n < CC) {
            float4 wa = *reinterpret_cast<const float4*>(Wout + n * DD + k0);
            float4 wb = *reinterpret_cast<const float4*>(Wout + n * DD + k0 + 4);
            o.x = pack2(wa.x, wa.y); o.y = pack2(wa.z, wa.w);
            o.z = pack2(wb.x, wb.y); o.w = pack2(wb.z, wb.w);
        }
        *reinterpret_cast<uint4*>(pBout + (size_t)r * 4) = o;
    }
}

// ---------------------------------------------------------------------------
// partition edges into fixed-capacity bucket regions (block-exclusive runs)
__global__ __launch_bounds__(256)
void k_partition(const int* __restrict__ src, const int* __restrict__ dst,
                 int* __restrict__ bcur, uint* __restrict__ tmp, int E) {
    __shared__ int h[NBK];
    __shared__ int cur[NBK];
    int chunk = (E + gridDim.x - 1) / gridDim.x;
    int lo = blockIdx.x * chunk;
    int hi = min(lo + chunk, E);
    for (int i = threadIdx.x; i < NBK; i += 256) h[i] = 0;
    __syncthreads();
    for (int i = lo + threadIdx.x; i < hi; i += 256)
        atomicAdd(&h[dst[i] >> BSH], 1);
    __syncthreads();
    for (int i = threadIdx.x; i < NBK; i += 256) {
        int c = h[i];
        cur[i] = c ? atomicAdd(&bcur[i], c) : 0;
    }
    __syncthreads();
    for (int i = lo + threadIdx.x; i < hi; i += 256) {
        int d = dst[i];
        int bkt = d >> BSH;
        int rel = atomicAdd(&cur[bkt], 1);
        if (rel < CAPT)
            tmp[(size_t)bkt * CAPT + rel] =
                ((uint)(d & (BSZ - 1)) << 17) | (uint)src[i];
    }
}

// per-bucket: LDS hist + padded scan -> rowinfo{start,cnt}; scatter; dummy fill
__global__ __launch_bounds__(256)
void k_bucket(const uint* __restrict__ tmp, const int* __restrict__ bcnt,
              int2* __restrict__ rowinfo, int* __restrict__ adj) {
    __shared__ int cnt[BSZ];
    __shared__ int cur[BSZ];
    __shared__ int ps[256];
    int b = blockIdx.x, t = threadIdx.x;
    int count = min(bcnt[b], CAPT);
    const uint* tb = tmp + (size_t)b * CAPT;
    int bbP = b * CAPP;
    cnt[t] = 0; cnt[t + 256] = 0;
    __syncthreads();
    for (int i = t; i < count; i += 256)
        atomicAdd(&cnt[tb[i] >> 17], 1);
    __syncthreads();
    int c0 = cnt[2 * t], c1 = cnt[2 * t + 1];
    int p0 = (c0 + 3) & ~3, p1 = (c1 + 3) & ~3;
    ps[t] = p0 + p1;
    __syncthreads();
    for (int off = 1; off < 256; off <<= 1) {
        int add = (t >= off) ? ps[t - off] : 0;
        __syncthreads();
        ps[t] += add;
        __syncthreads();
    }
    int ex = ps[t] - (p0 + p1);
    cur[2 * t] = ex; cur[2 * t + 1] = ex + p0;
    int node0 = b * BSZ;
    if (node0 + 2 * t < NN)     rowinfo[node0 + 2 * t]     = make_int2(bbP + ex, c0);
    if (node0 + 2 * t + 1 < NN) rowinfo[node0 + 2 * t + 1] = make_int2(bbP + ex + p0, c1);
    __syncthreads();
    for (int i = t; i < count; i += 256) {
        uint e = tb[i];
        int pos = bbP + atomicAdd(&cur[e >> 17], 1);
        adj[pos] = (int)(e & 0x1FFFFu);
    }
    __syncthreads();
    // dummy slots -> zero row NN
    for (int q = c0; q < p0; ++q) adj[bbP + ex + q] = NN;
    int ex1 = ex + p0;
    for (int q = c1; q < p1; ++q) adj[bbP + ex1 + q] = NN;
}

// ---------------------------------------------------------------------------
// gather-aggregate: one wave/node; wave-uniform control scalarized via
// readfirstlane -> s_load adj + SGPR-base row gathers (voffset = lane*4)
__global__ __launch_bounds__(256)
void k_aggregate(const int2* __restrict__ rowinfo, const int* __restrict__ adj,
                 const uint* __restrict__ xh, uint* __restrict__ outm) {
    int w = blockIdx.x * 4 + __builtin_amdgcn_readfirstlane(threadIdx.x >> 6);
    int lane = threadIdx.x & 63;
    int2 ri = rowinfo[w];
    int beg = __builtin_amdgcn_readfirstlane(ri.x);
    int n   = __builtin_amdgcn_readfirstlane(ri.y);
    int end = beg + ((n + 3) & ~3);
    float s0 = 0.f, s1 = 0.f, s2 = 0.f, s3 = 0.f;
    float s4 = 0.f, s5 = 0.f, s6 = 0.f, s7 = 0.f;
    #pragma unroll 2
    for (int j = beg; j < end; j += 4) {
        int4 nb = *reinterpret_cast<const int4*>(adj + j);
        int n0 = __builtin_amdgcn_readfirstlane(nb.x);
        int n1 = __builtin_amdgcn_readfirstlane(nb.y);
        int n2 = __builtin_amdgcn_readfirstlane(nb.z);
        int n3 = __builtin_amdgcn_readfirstlane(nb.w);
        uint v0 = (xh + (size_t)n0 * 64)[lane];
        uint v1 = (xh + (size_t)n1 * 64)[lane];
        uint v2 = (xh + (size_t)n2 * 64)[lane];
        uint v3 = (xh + (size_t)n3 * 64)[lane];
        s0 += blo(v0); s1 += bhi(v0);
        s2 += blo(v1); s3 += bhi(v1);
        s4 += blo(v2); s5 += bhi(v2);
        s6 += blo(v3); s7 += bhi(v3);
    }
    float inv = 1.0f / fmaxf((float)n, 1.0f);
    outm[(uint)(w * 64 + lane)] = pack2((s0 + s2 + s4 + s6) * inv,
                                        (s1 + s3 + s5 + s7) * inv);
}

// ---------------------------------------------------------------------------
// MFMA fused SAGE linear: h = relu([mean|xin] @ packedW + bias)
// HEAD=false: store h as bf16.  HEAD=true: keep h in LDS, apply classifier
// head (h @ Wout^T + bout) via MFMA, store f32 logits directly.
template <bool HEAD>
__global__ __launch_bounds__(256)
void k_linear_t(const ushort* __restrict__ mean, const ushort* __restrict__ xin,
                const uint* __restrict__ pB, const float* __restrict__ bias,
                ushort* __restrict__ outh,
                const uint* __restrict__ pBout, const float* __restrict__ bout,
                float* __restrict__ outf)
{
    __shared__ u32x4 sB[4096];   // 64 KB: [kb][nt][lane] 16B frags
    const int tid = threadIdx.x;
    const u32x4* pBv = reinterpret_cast<const u32x4*>(pB);
    #pragma unroll
    for (int i = 0; i < 16; ++i)
        sB[tid + i * 256] = pBv[tid + i * 256];

    const int w = tid >> 6, l = tid & 63;
    const int fq = l >> 4, fr = l & 15;
    const int rbase = blockIdx.x * 128 + w * 32;   // wave-exclusive 32 rows

    f32x4 acc[2][8] = {};
    __syncthreads();

    #pragma unroll
    for (int kb = 0; kb < 8; ++kb) {
        const ushort* In = (kb < 4) ? mean : xin;
        const int ko = (kb & 3) * 32 + fq * 8;
        s16x8 a0 = __builtin_bit_cast(s16x8,
            *reinterpret_cast<const u32x4*>(In + (size_t)(rbase + fr) * DD + ko));
        s16x8 a1 = __builtin_bit_cast(s16x8,
            *reinterpret_cast<const u32x4*>(In + (size_t)(rbase + 16 + fr) * DD + ko));
        #pragma unroll
        for (int nt = 0; nt < 8; ++nt) {
            s16x8 b = __builtin_bit_cast(s16x8, sB[(kb * 8 + nt) * 64 + l]);
            acc[0][nt] = __builtin_amdgcn_mfma_f32_16x16x32_bf16(a0, b, acc[0][nt], 0, 0, 0);
            acc[1][nt] = __builtin_amdgcn_mfma_f32_16x16x32_bf16(a1, b, acc[1][nt], 0, 0, 0);
        }
    }

    if constexpr (!HEAD) {
        // epilogue: bias + relu + bf16 pack; D: col=fr (per nt), row=fq*4+reg
        #pragma unroll
        for (int nt = 0; nt < 8; ++nt) {
            float bn = bias[nt * 16 + fr];
            #pragma unroll
            for (int m = 0; m < 2; ++m) {
                int row = rbase + m * 16 + fq * 4;
                #pragma unroll
                for (int reg = 0; reg < 4; ++reg) {
                    int r = row + reg;
                    if (r < NN) {
                        float o = fmaxf(acc[m][nt][reg] + bn, 0.0f);
                        outh[(size_t)r * DD + nt * 16 + fr] = (ushort)f2b(o);
                    }
                }
            }
        }
    } else {
        __syncthreads();                     // all sB reads done; reuse as sH
        ushort* sH = reinterpret_cast<ushort*>(sB);
        const int LDH = 136;                 // +8 ushort pad (16B) per row
        #pragma unroll
        for (int nt = 0; nt < 8; ++nt) {
            float bn = bias[nt * 16 + fr];
            #pragma unroll
            for (int m = 0; m < 2; ++m) {
                #pragma unroll
                for (int reg = 0; reg < 4; ++reg) {
                    int lrow = w * 32 + m * 16 + fq * 4 + reg;
                    float o = fmaxf(acc[m][nt][reg] + bn, 0.0f);
                    sH[lrow * LDH + nt * 16 + fr] = (ushort)f2b(o);
                }
            }
        }
        __syncthreads();
        f32x4 oa[2][3] = {};
        #pragma unroll
        for (int kb2 = 0; kb2 < 4; ++kb2) {
            s16x8 a0 = *reinterpret_cast<const s16x8*>(
                sH + (w * 32 + fr) * LDH + kb2 * 32 + fq * 8);
            s16x8 a1 = *reinterpret_cast<const s16x8*>(
                sH + (w * 32 + 16 + fr) * LDH + kb2 * 32 + fq * 8);
            #pragma unroll
            for (int nt2 = 0; nt2 < 3; ++nt2) {
                s16x8 b = __builtin_bit_cast(s16x8,
                    *reinterpret_cast<const u32x4*>(
                        pBout + (size_t)((kb2 * 3 + nt2) * 64 + l) * 4));
                oa[0][nt2] = __builtin_amdgcn_mfma_f32_16x16x32_bf16(a0, b, oa[0][nt2], 0, 0, 0);
                oa[1][nt2] = __builtin_amdgcn_mfma_f32_16x16x32_bf16(a1, b, oa[1][nt2], 0, 0, 0);
            }
        }
        #pragma unroll
        for (int nt2 = 0; nt2 < 3; ++nt2) {
            int col = nt2 * 16 + fr;
            if (col < CC) {
                float bn = bout[col];
                #pragma unroll
                for (int m = 0; m < 2; ++m) {
                    #pragma unroll
                    for (int reg = 0; reg < 4; ++reg) {
                        int r = rbase + m * 16 + fq * 4 + reg;
                        if (r < NN)
                            outf[(size_t)r * CC + col] = oa[m][nt2][reg] + bn;
                    }
                }
            }
        }
    }
}

// ---------------------------------------------------------------------------
extern "C" void kernel_launch(void* const* d_in, const int* in_sizes, int n_in,
                              void* d_out, int out_size, void* d_ws, size_t ws_size,
                              hipStream_t stream)
{
    const float* x    = (const float*)d_in[0];
    const int*   ei   = (const int*)d_in[1];
    const float* Wl1  = (const float*)d_in[2];
    const float* bl1  = (const float*)d_in[3];
    const float* Wr1  = (const float*)d_in[4];
    const float* Wl2  = (const float*)d_in[5];
    const float* bl2  = (const float*)d_in[6];
    const float* Wr2  = (const float*)d_in[7];
    const float* Wout = (const float*)d_in[8];
    const float* bout = (const float*)d_in[9];
    float* out = (float*)d_out;

    const int E = in_sizes[1] / 2;
    const int* srcI = ei;        // edge_index[0]
    const int* dstI = ei + E;    // edge_index[1]

    // workspace layout:
    // xh [(N+1)*64 uint] | m [N*64] | h1 [(N+1)*64] | rowinfo int2[N] |
    // adj [NBK*CAPP] | tmp [NBK*CAPT] | bcur [NBK] | pB1 | pB2 | pBout
    ushort* xh = (ushort*)d_ws;
    ushort* m  = xh + (size_t)(NN + 1) * DD;
    ushort* h1 = m + (size_t)NN * DD;
    int2* rowinfo = (int2*)(h1 + (size_t)(NN + 1) * DD);
    int* adj  = (int*)(rowinfo + NN);
    uint* tmp = (uint*)(adj + (size_t)NBK * CAPP);
    int* bcur = (int*)(tmp + (size_t)NBK * CAPT);
    uintptr_t pb = ((uintptr_t)(bcur + NBK) + 15) & ~(uintptr_t)15;
    uint* pB1   = (uint*)pb;
    uint* pB2   = pB1 + 16384;
    uint* pBout = pB2 + 16384;

    dim3 b256(256);
    const int aggBlocks = NN / 4;            // one wave per node
    const int linBlocks = (NN + 127) / 128;
    const int n8 = NN * DD / 8;

    // ---- convert x to bf16 (+ dummy rows), pack weights, CSR build
    k_cvt<<<(n8 + 255) / 256, b256, 0, stream>>>(x, (uint*)xh, (uint*)h1, n8);
    k_prepw<<<35, b256, 0, stream>>>(Wl1, Wr1, Wl2, Wr2, Wout, pB1, pB2, pBout);
    hipMemsetAsync(bcur, 0, NBK * sizeof(int), stream);
    k_partition<<<256, b256, 0, stream>>>(srcI, dstI, bcur, tmp, E);
    k_bucket<<<NBK, b256, 0, stream>>>(tmp, bcur, rowinfo, adj);

    // ---- layer 1
    k_aggregate<<<aggBlocks, b256, 0, stream>>>(rowinfo, adj, (const uint*)xh, (uint*)m);
    k_linear_t<false><<<linBlocks, b256, 0, stream>>>(m, xh, pB1, bl1, h1,
                                                      nullptr, nullptr, nullptr);

    // ---- layer 2 + fused classifier head
    k_aggregate<<<aggBlocks, b256, 0, stream>>>(rowinfo, adj, (const uint*)h1, (uint*)m);
    k_linear_t<true><<<linBlocks, b256, 0, stream>>>(m, h1, pB2, bl2, nullptr,
                                                     pBout, bout, out);
}

// Round 9
// 217.763 us; speedup vs baseline: 26.3282x; 1.0783x over previous
//
#include <hip/hip_runtime.h>

#define NN 100000
#define DD 128
#define CC 40
#define BSH 9                      // bucket = dst >> 9
#define BSZ 512                    // nodes per bucket
#define NBK ((NN + BSZ - 1) / BSZ) // 196 buckets
#define CAPT 10240                 // tmp slots per bucket (mean 8163, sigma 90)
#define CAPP (CAPT + 3 * BSZ)      // padded adj slots per bucket = 11776

typedef unsigned int  uint;
typedef unsigned short ushort;

typedef __attribute__((ext_vector_type(8))) short  s16x8;   // 8 bf16 (4 VGPRs)
typedef __attribute__((ext_vector_type(4))) float  f32x4;
typedef __attribute__((ext_vector_type(4))) uint   u32x4;

// bf16 helpers (bit-level, round-to-nearest-even)
__device__ __forceinline__ float blo(uint u) { return __uint_as_float(u << 16); }
__device__ __forceinline__ float bhi(uint u) { return __uint_as_float(u & 0xFFFF0000u); }
__device__ __forceinline__ uint  f2b(float f) {
    uint u = __float_as_uint(f);
    return (u + 0x7FFFu + ((u >> 16) & 1u)) >> 16;
}
__device__ __forceinline__ uint pack2(float lo, float hi) { return f2b(lo) | (f2b(hi) << 16); }

// ---------------------------------------------------------------------------
// x (f32) -> xh (bf16), 8 elems/thread; also zeros dummy row NN of xh and h1
__global__ __launch_bounds__(256)
void k_cvt(const float* __restrict__ x, uint* __restrict__ xh,
           uint* __restrict__ h1, int n8) {
    int i = blockIdx.x * 256 + threadIdx.x;
    if (i < 16) {
        u32x4 z = {0, 0, 0, 0};
        reinterpret_cast<u32x4*>(xh + (size_t)NN * 64)[i] = z;
        reinterpret_cast<u32x4*>(h1 + (size_t)NN * 64)[i] = z;
    }
    if (i >= n8) return;
    float4 a = reinterpret_cast<const float4*>(x)[i * 2];
    float4 b = reinterpret_cast<const float4*>(x)[i * 2 + 1];
    uint4 o;
    o.x = pack2(a.x, a.y); o.y = pack2(a.z, a.w);
    o.z = pack2(b.x, b.y); o.w = pack2(b.z, b.w);
    reinterpret_cast<uint4*>(xh)[i] = o;
}

// ---------------------------------------------------------------------------
// pack weights into bf16 MFMA B-operand fragments.
__global__ __launch_bounds__(256)
void k_prepw(const float* __restrict__ Wl1, const float* __restrict__ Wr1,
             const float* __restrict__ Wl2, const float* __restrict__ Wr2,
             const float* __restrict__ Wout,
             uint* __restrict__ pB1, uint* __restrict__ pB2,
             uint* __restrict__ pBout) {
    int t = blockIdx.x * 256 + threadIdx.x;   // 0..8959
    if (t < 8192) {
        int layer = t >> 12;
        int r = t & 4095;
        int kb = r >> 9, nt = (r >> 6) & 7, l = r & 63;
        int n  = nt * 16 + (l & 15);
        int k0 = kb * 32 + ((l >> 4) << 3);       // chunk never straddles 128
        const float* W = (k0 < 128) ? (layer ? Wl2 : Wl1) : (layer ? Wr2 : Wr1);
        int kk = k0 & 127;
        float4 wa = *reinterpret_cast<const float4*>(W + n * DD + kk);
        float4 wb = *reinterpret_cast<const float4*>(W + n * DD + kk + 4);
        uint4 o;
        o.x = pack2(wa.x, wa.y); o.y = pack2(wa.z, wa.w);
        o.z = pack2(wb.x, wb.y); o.w = pack2(wb.z, wb.w);
        uint* pB = layer ? pB2 : pB1;
        *reinterpret_cast<uint4*>(pB + (size_t)r * 4) = o;
    } else if (t < 8960) {
        int r = t - 8192;                          // 0..767
        int kb = r / 192, rem = r % 192;
        int nt = rem >> 6, l = rem & 63;
        int n  = nt * 16 + (l & 15);
        int k0 = kb * 32 + ((l >> 4) << 3);
        uint4 o = {0, 0, 0, 0};
        if (n < CC) {
            float4 wa = *reinterpret_cast<const float4*>(Wout + n * DD + k0);
            float4 wb = *reinterpret_cast<const float4*>(Wout + n * DD + k0 + 4);
            o.x = pack2(wa.x, wa.y); o.y = pack2(wa.z, wa.w);
            o.z = pack2(wb.x, wb.y); o.w = pack2(wb.z, wb.w);
        }
        *reinterpret_cast<uint4*>(pBout + (size_t)r * 4) = o;
    }
}

// ---------------------------------------------------------------------------
// partition edges into fixed-capacity bucket regions (block-exclusive runs)
__global__ __launch_bounds__(256)
void k_partition(const int* __restrict__ src, const int* __restrict__ dst,
                 int* __restrict__ bcur, uint* __restrict__ tmp, int E) {
    __shared__ int h[NBK];
    __shared__ int cur[NBK];
    int chunk = (E + gridDim.x - 1) / gridDim.x;
    int lo = blockIdx.x * chunk;
    int hi = min(lo + chunk, E);
    for (int i = threadIdx.x; i < NBK; i += 256) h[i] = 0;
    __syncthreads();
    for (int i = lo + threadIdx.x; i < hi; i += 256)
        atomicAdd(&h[dst[i] >> BSH], 1);
    __syncthreads();
    for (int i = threadIdx.x; i < NBK; i += 256) {
        int c = h[i];
        cur[i] = c ? atomicAdd(&bcur[i], c) : 0;
    }
    __syncthreads();
    for (int i = lo + threadIdx.x; i < hi; i += 256) {
        int d = dst[i];
        int bkt = d >> BSH;
        int rel = atomicAdd(&cur[bkt], 1);
        if (rel < CAPT)
            tmp[(size_t)bkt * CAPT + rel] =
                ((uint)(d & (BSZ - 1)) << 17) | (uint)src[i];
    }
}

// per-bucket: LDS hist + padded scan -> rowinfo{start,cnt}; scatter; dummy fill
__global__ __launch_bounds__(256)
void k_bucket(const uint* __restrict__ tmp, const int* __restrict__ bcnt,
              int2* __restrict__ rowinfo, int* __restrict__ adj) {
    __shared__ int cnt[BSZ];
    __shared__ int cur[BSZ];
    __shared__ int ps[256];
    int b = blockIdx.x, t = threadIdx.x;
    int count = min(bcnt[b], CAPT);
    const uint* tb = tmp + (size_t)b * CAPT;
    int bbP = b * CAPP;
    cnt[t] = 0; cnt[t + 256] = 0;
    __syncthreads();
    for (int i = t; i < count; i += 256)
        atomicAdd(&cnt[tb[i] >> 17], 1);
    __syncthreads();
    int c0 = cnt[2 * t], c1 = cnt[2 * t + 1];
    int p0 = (c0 + 3) & ~3, p1 = (c1 + 3) & ~3;
    ps[t] = p0 + p1;
    __syncthreads();
    for (int off = 1; off < 256; off <<= 1) {
        int add = (t >= off) ? ps[t - off] : 0;
        __syncthreads();
        ps[t] += add;
        __syncthreads();
    }
    int ex = ps[t] - (p0 + p1);
    cur[2 * t] = ex; cur[2 * t + 1] = ex + p0;
    int node0 = b * BSZ;
    if (node0 + 2 * t < NN)     rowinfo[node0 + 2 * t]     = make_int2(bbP + ex, c0);
    if (node0 + 2 * t + 1 < NN) rowinfo[node0 + 2 * t + 1] = make_int2(bbP + ex + p0, c1);
    __syncthreads();
    for (int i = t; i < count; i += 256) {
        uint e = tb[i];
        int pos = bbP + atomicAdd(&cur[e >> 17], 1);
        adj[pos] = (int)(e & 0x1FFFFu);
    }
    __syncthreads();
    // dummy slots -> zero row NN
    for (int q = c0; q < p0; ++q) adj[bbP + ex + q] = NN;
    int ex1 = ex + p0;
    for (int q = c1; q < p1; ++q) adj[bbP + ex1 + q] = NN;
}

// ---------------------------------------------------------------------------
// gather-aggregate: one wave/node. Pair-split gathers: lanes 0-31 read 8B of
// row A, lanes 32-63 read 8B of row B -> 512B/instr, 16 rows in flight.
__global__ __launch_bounds__(256)
void k_aggregate(const int2* __restrict__ rowinfo, const int* __restrict__ adj,
                 const uint* __restrict__ xh, uint* __restrict__ outm) {
    const int lane = threadIdx.x & 63;
    const int w = blockIdx.x * 4 + __builtin_amdgcn_readfirstlane(threadIdx.x >> 6);
    int2 ri = rowinfo[w];
    const int beg = __builtin_amdgcn_readfirstlane(ri.x);
    const int n   = __builtin_amdgcn_readfirstlane(ri.y);
    const int end = beg + ((n + 3) & ~3);
    const uint co = (uint)((lane & 31) << 1);   // uint offset within row

    float a0 = 0.f, a1 = 0.f, a2 = 0.f, a3 = 0.f;
    float b0 = 0.f, b1 = 0.f, b2 = 0.f, b3 = 0.f;

    int j = beg;
    #pragma unroll 2
    for (; j + 8 <= end; j += 8) {
        int4 nA = *reinterpret_cast<const int4*>(adj + j);
        int4 nB = *reinterpret_cast<const int4*>(adj + j + 4);
        int r0 = (lane < 32) ? nA.x : nA.y;
        int r1 = (lane < 32) ? nA.z : nA.w;
        int r2 = (lane < 32) ? nB.x : nB.y;
        int r3 = (lane < 32) ? nB.z : nB.w;
        uint2 v0 = *reinterpret_cast<const uint2*>(xh + ((uint)r0 << 6) + co);
        uint2 v1 = *reinterpret_cast<const uint2*>(xh + ((uint)r1 << 6) + co);
        uint2 v2 = *reinterpret_cast<const uint2*>(xh + ((uint)r2 << 6) + co);
        uint2 v3 = *reinterpret_cast<const uint2*>(xh + ((uint)r3 << 6) + co);
        a0 += blo(v0.x); a1 += bhi(v0.x); a2 += blo(v0.y); a3 += bhi(v0.y);
        b0 += blo(v1.x); b1 += bhi(v1.x); b2 += blo(v1.y); b3 += bhi(v1.y);
        a0 += blo(v2.x); a1 += bhi(v2.x); a2 += blo(v2.y); a3 += bhi(v2.y);
        b0 += blo(v3.x); b1 += bhi(v3.x); b2 += blo(v3.y); b3 += bhi(v3.y);
    }
    if (j < end) {                       // exactly 4 padded rows remain
        int4 nA = *reinterpret_cast<const int4*>(adj + j);
        int r0 = (lane < 32) ? nA.x : nA.y;
        int r1 = (lane < 32) ? nA.z : nA.w;
        uint2 v0 = *reinterpret_cast<const uint2*>(xh + ((uint)r0 << 6) + co);
        uint2 v1 = *reinterpret_cast<const uint2*>(xh + ((uint)r1 << 6) + co);
        a0 += blo(v0.x); a1 += bhi(v0.x); a2 += blo(v0.y); a3 += bhi(v0.y);
        b0 += blo(v1.x); b1 += bhi(v1.x); b2 += blo(v1.y); b3 += bhi(v1.y);
    }

    float t0 = a0 + b0, t1 = a1 + b1, t2 = a2 + b2, t3 = a3 + b3;
    t0 += __shfl_xor(t0, 32);            // fold odd-row half into lanes 0-31
    t1 += __shfl_xor(t1, 32);
    t2 += __shfl_xor(t2, 32);
    t3 += __shfl_xor(t3, 32);
    if (lane < 32) {
        float inv = 1.0f / fmaxf((float)n, 1.0f);
        uint2 o;
        o.x = pack2(t0 * inv, t1 * inv);
        o.y = pack2(t2 * inv, t3 * inv);
        *reinterpret_cast<uint2*>(outm + (uint)(w * 64) + ((uint)lane << 1)) = o;
    }
}

// ---------------------------------------------------------------------------
// MFMA fused SAGE linear: h = relu([mean|xin] @ packedW + bias)
// HEAD=false: h -> LDS -> coalesced bf16 store.
// HEAD=true:  h -> LDS, classifier head (h @ Wout^T + bout) via MFMA -> f32.
template <bool HEAD>
__global__ __launch_bounds__(256)
void k_linear_t(const ushort* __restrict__ mean, const ushort* __restrict__ xin,
                const uint* __restrict__ pB, const float* __restrict__ bias,
                ushort* __restrict__ outh,
                const uint* __restrict__ pBout, const float* __restrict__ bout,
                float* __restrict__ outf)
{
    __shared__ u32x4 sB[4096];   // 64 KB: [kb][nt][lane] 16B frags
    const int tid = threadIdx.x;
    const u32x4* pBv = reinterpret_cast<const u32x4*>(pB);
    #pragma unroll
    for (int i = 0; i < 16; ++i)
        sB[tid + i * 256] = pBv[tid + i * 256];

    const int w = tid >> 6, l = tid & 63;
    const int fq = l >> 4, fr = l & 15;
    const int rbase = blockIdx.x * 128 + w * 32;   // wave-exclusive 32 rows

    f32x4 acc[2][8] = {};
    __syncthreads();

    #pragma unroll
    for (int kb = 0; kb < 8; ++kb) {
        const ushort* In = (kb < 4) ? mean : xin;
        const int ko = (kb & 3) * 32 + fq * 8;
        s16x8 a0 = __builtin_bit_cast(s16x8,
            *reinterpret_cast<const u32x4*>(In + (size_t)(rbase + fr) * DD + ko));
        s16x8 a1 = __builtin_bit_cast(s16x8,
            *reinterpret_cast<const u32x4*>(In + (size_t)(rbase + 16 + fr) * DD + ko));
        #pragma unroll
        for (int nt = 0; nt < 8; ++nt) {
            s16x8 b = __builtin_bit_cast(s16x8, sB[(kb * 8 + nt) * 64 + l]);
            acc[0][nt] = __builtin_amdgcn_mfma_f32_16x16x32_bf16(a0, b, acc[0][nt], 0, 0, 0);
            acc[1][nt] = __builtin_amdgcn_mfma_f32_16x16x32_bf16(a1, b, acc[1][nt], 0, 0, 0);
        }
    }

    __syncthreads();                     // all sB reads done; reuse as sH
    ushort* sH = reinterpret_cast<ushort*>(sB);
    const int LDH = 136;                 // +8 ushort pad (16B) per row
    #pragma unroll
    for (int nt = 0; nt < 8; ++nt) {
        float bn = bias[nt * 16 + fr];
        #pragma unroll
        for (int m = 0; m < 2; ++m) {
            #pragma unroll
            for (int reg = 0; reg < 4; ++reg) {
                int lrow = w * 32 + m * 16 + fq * 4 + reg;
                float o = fmaxf(acc[m][nt][reg] + bn, 0.0f);
                sH[lrow * LDH + nt * 16 + fr] = (ushort)f2b(o);
            }
        }
    }
    __syncthreads();

    if constexpr (!HEAD) {
        // coalesced bf16 store: 128 rows x 16 chunks of 16B = 2048 chunks
        #pragma unroll
        for (int k2 = 0; k2 < 8; ++k2) {
            int idx = k2 * 256 + tid;
            int row = idx >> 4, seg = idx & 15;
            int gr = blockIdx.x * 128 + row;
            if (gr < NN) {
                u32x4 v = *reinterpret_cast<const u32x4*>(sH + row * LDH + seg * 8);
                *reinterpret_cast<u32x4*>(outh + (size_t)gr * DD + seg * 8) = v;
            }
        }
    } else {
        f32x4 oa[2][3] = {};
        #pragma unroll
        for (int kb2 = 0; kb2 < 4; ++kb2) {
            s16x8 a0 = *reinterpret_cast<const s16x8*>(
                sH + (w * 32 + fr) * LDH + kb2 * 32 + fq * 8);
            s16x8 a1 = *reinterpret_cast<const s16x8*>(
                sH + (w * 32 + 16 + fr) * LDH + kb2 * 32 + fq * 8);
            #pragma unroll
            for (int nt2 = 0; nt2 < 3; ++nt2) {
                s16x8 b = __builtin_bit_cast(s16x8,
                    *reinterpret_cast<const u32x4*>(
                        pBout + (size_t)((kb2 * 3 + nt2) * 64 + l) * 4));
                oa[0][nt2] = __builtin_amdgcn_mfma_f32_16x16x32_bf16(a0, b, oa[0][nt2], 0, 0, 0);
                oa[1][nt2] = __builtin_amdgcn_mfma_f32_16x16x32_bf16(a1, b, oa[1][nt2], 0, 0, 0);
            }
        }
        #pragma unroll
        for (int nt2 = 0; nt2 < 3; ++nt2) {
            int col = nt2 * 16 + fr;
            if (col < CC) {
                float bn = bout[col];
                #pragma unroll
                for (int m = 0; m < 2; ++m) {
                    #pragma unroll
                    for (int reg = 0; reg < 4; ++reg) {
                        int r = rbase + m * 16 + fq * 4 + reg;
                        if (r < NN)
                            outf[(size_t)r * CC + col] = oa[m][nt2][reg] + bn;
                    }
                }
            }
        }
    }
}

// ---------------------------------------------------------------------------
extern "C" void kernel_launch(void* const* d_in, const int* in_sizes, int n_in,
                              void* d_out, int out_size, void* d_ws, size_t ws_size,
                              hipStream_t stream)
{
    const float* x    = (const float*)d_in[0];
    const int*   ei   = (const int*)d_in[1];
    const float* Wl1  = (const float*)d_in[2];
    const float* bl1  = (const float*)d_in[3];
    const float* Wr1  = (const float*)d_in[4];
    const float* Wl2  = (const float*)d_in[5];
    const float* bl2  = (const float*)d_in[6];
    const float* Wr2  = (const float*)d_in[7];
    const float* Wout = (const float*)d_in[8];
    const float* bout = (const float*)d_in[9];
    float* out = (float*)d_out;

    const int E = in_sizes[1] / 2;
    const int* srcI = ei;        // edge_index[0]
    const int* dstI = ei + E;    // edge_index[1]

    // workspace layout:
    // xh [(N+1)*64 uint] | m [N*64] | h1 [(N+1)*64] | rowinfo int2[N] |
    // adj [NBK*CAPP] | tmp [NBK*CAPT] | bcur [NBK] | pB1 | pB2 | pBout
    ushort* xh = (ushort*)d_ws;
    ushort* m  = xh + (size_t)(NN + 1) * DD;
    ushort* h1 = m + (size_t)NN * DD;
    int2* rowinfo = (int2*)(h1 + (size_t)(NN + 1) * DD);
    int* adj  = (int*)(rowinfo + NN);
    uint* tmp = (uint*)(adj + (size_t)NBK * CAPP);
    int* bcur = (int*)(tmp + (size_t)NBK * CAPT);
    uintptr_t pb = ((uintptr_t)(bcur + NBK) + 15) & ~(uintptr_t)15;
    uint* pB1   = (uint*)pb;
    uint* pB2   = pB1 + 16384;
    uint* pBout = pB2 + 16384;

    dim3 b256(256);
    const int aggBlocks = NN / 4;            // one wave per node
    const int linBlocks = (NN + 127) / 128;
    const int n8 = NN * DD / 8;

    // ---- convert x to bf16 (+ dummy rows), pack weights, CSR build
    k_cvt<<<(n8 + 255) / 256, b256, 0, stream>>>(x, (uint*)xh, (uint*)h1, n8);
    k_prepw<<<35, b256, 0, stream>>>(Wl1, Wr1, Wl2, Wr2, Wout, pB1, pB2, pBout);
    hipMemsetAsync(bcur, 0, NBK * sizeof(int), stream);
    k_partition<<<256, b256, 0, stream>>>(srcI, dstI, bcur, tmp, E);
    k_bucket<<<NBK, b256, 0, stream>>>(tmp, bcur, rowinfo, adj);

    // ---- layer 1
    k_aggregate<<<aggBlocks, b256, 0, stream>>>(rowinfo, adj, (const uint*)xh, (uint*)m);
    k_linear_t<false><<<linBlocks, b256, 0, stream>>>(m, xh, pB1, bl1, h1,
                                                      nullptr, nullptr, nullptr);

    // ---- layer 2 + fused classifier head
    k_aggregate<<<aggBlocks, b256, 0, stream>>>(rowinfo, adj, (const uint*)h1, (uint*)m);
    k_linear_t<true><<<linBlocks, b256, 0, stream>>>(m, h1, pB2, bl2, nullptr,
                                                     pBout, bout, out);
}